// Round 2
// baseline (1102.662 us; speedup 1.0000x reference)
//
#include <hip/hip_runtime.h>
#include <hip/hip_bf16.h>
#include <cstdint>
#include <cstddef>
#include <math.h>

// ---------------- problem constants ----------------
#define T_TOK 1035      // TOTAL_TOKENS
#define BT    2070      // B*T
#define NE    2048      // n_embd
#define NH    16
#define HD    128
#define CACHE_SZ 5175
#define SINK  1035
#define MAXA  4140      // LOCAL_ATTN_SIZE*TOTAL_TOKENS
#define KPAD  4160      // MAXA rounded up to 64
#define PRE   11        // POSE+YAW
#define WN    4194304   // 2048*2048
#define XN    4239360   // 2070*2048

typedef unsigned short u16;
typedef __attribute__((ext_vector_type(8))) short bf16x8;
typedef __attribute__((ext_vector_type(4))) float f32x4;

__device__ __forceinline__ u16 f2bf(float f) {
  union { float f; uint32_t u; } v; v.f = f;
  return (u16)((v.u + 0x7FFFu + ((v.u >> 16) & 1)) >> 16);
}
__device__ __forceinline__ uint32_t pack2(float a, float b) {
  return (uint32_t)f2bf(a) | ((uint32_t)f2bf(b) << 16);
}

typedef __attribute__((address_space(1))) const void gvoid;
typedef __attribute__((address_space(3))) void lvoid;
__device__ __forceinline__ void gload16(const void* g, void* l) {
  __builtin_amdgcn_global_load_lds((gvoid*)g, (lvoid*)l, 16, 0, 0);
}
__device__ __forceinline__ f32x4 mfma16(bf16x8 a, bf16x8 b, f32x4 c) {
  return __builtin_amdgcn_mfma_f32_16x16x32_bf16(a, b, c, 0, 0, 0);
}

// ---------------- cache-window arithmetic (device, from runtime scalars) ----
struct CacheMap {
  int cache_start, klen, pos_new;   // pos_new: eff-index where new tokens begin
  int num_evicted, num_rolled;
  bool evict;
};
__device__ __forceinline__ CacheMap cache_map(int cs, int ge, int le) {
  CacheMap m;
  const int ce = cs + T_TOK;
  m.evict = (ce > ge) && (T_TOK + le > CACHE_SZ);
  int nle;
  if (m.evict) {
    m.num_evicted = T_TOK + le - CACHE_SZ;
    m.num_rolled  = le - m.num_evicted - SINK;
    nle = le + (ce - ge) - m.num_evicted;
    m.pos_new = SINK + m.num_rolled;
  } else {
    m.num_evicted = 0; m.num_rolled = 0;
    nle = le + (ce - ge);
    m.pos_new = nle - T_TOK;
  }
  int csrt = nle - MAXA; if (csrt < 0) csrt = 0;
  m.cache_start = csrt;
  m.klen = nle - csrt;
  return m;
}
// eff index -> cache token index (>=0) or new-token t encoded as -1-t
__device__ __forceinline__ int eff_src(const CacheMap& m, int e) {
  if (m.evict) {
    if (e < SINK) return e;
    if (e < m.pos_new) return e + m.num_evicted;
    return -1 - (e - m.pos_new);
  } else {
    if (e < m.pos_new) return e;
    return -1 - (e - m.pos_new);
  }
}

// ---------------- kernel 1: f32 -> bf16 convert (x + 4 weights) -------------
__global__ __launch_bounds__(256) void conv_bf16(
    const float* __restrict__ x, const float* __restrict__ wq,
    const float* __restrict__ wk, const float* __restrict__ wv,
    const float* __restrict__ wp, u16* __restrict__ xb, u16* __restrict__ wb) {
  const size_t i8 = ((size_t)blockIdx.x * 256 + threadIdx.x) * 8;
  if (i8 >= (size_t)XN + 4ull * WN) return;
  const float* src; u16* dst;
  if (i8 < XN) { src = x + i8; dst = xb + i8; }
  else {
    const size_t w = i8 - XN;
    const int m = (int)(w >> 22);
    const size_t o = w & (WN - 1);
    src = (m == 0 ? wq : m == 1 ? wk : m == 2 ? wv : wp) + o;
    dst = wb + w;
  }
  float4 a = *(const float4*)src;
  float4 c = *(const float4*)(src + 4);
  uint4 o;
  o.x = pack2(a.x, a.y); o.y = pack2(a.z, a.w);
  o.z = pack2(c.x, c.y); o.w = pack2(c.z, c.w);
  *(uint4*)dst = o;
}

// ---------------- kernel 2: axial RoPE tables [1024][64] --------------------
__global__ __launch_bounds__(256) void rope_tab_k(float* __restrict__ rc,
                                                  float* __restrict__ rs) {
  const int idx = blockIdx.x * 256 + threadIdx.x;   // 65536 entries
  const int t = idx >> 6, p = idx & 63;
  const int fi = p & 31;
  const float pos = (p < 32) ? (float)(t & 31) : (float)(t >> 5);
  const float freq = exp2f(-(float)fi * 0.31143075889569023f); // log2(1000)/32
  const float ang = pos * freq;
  rc[idx] = cosf(ang);
  rs[idx] = sinf(ang);
}

// ---------------- kernel 3/8: bf16 GEMM, C = A @ Bw^T (NT) ------------------
// MODE 0: A=x_bf16 (2070x2048), Bw = [Wq;Wk;Wv] (6144x2048) -> qpre/kpre f32, vtmp bf16
// MODE 1: A=y_bf16, Bw = Wproj -> out f32
template<int MODE>
__global__ __launch_bounds__(256) void gemm_k(const u16* __restrict__ A,
                                              const u16* __restrict__ Bw,
                                              float* __restrict__ o0,
                                              float* __restrict__ o1,
                                              u16* __restrict__ o2) {
  __shared__ u16 lA[128 * 64];
  __shared__ u16 lB[128 * 64];
  const int tid = threadIdx.x;
  const int m0 = blockIdx.x * 128;
  const int n0 = blockIdx.y * 128;
  const int lane = tid & 63, wid = tid >> 6;
  const int l4 = lane & 15, g = lane >> 4;
  const int wm = wid >> 1, wn = wid & 1;

  f32x4 acc[4][4] = {};

  const int srow = tid >> 3;          // 0..31
  const int cb = (tid & 7) * 16;      // byte col in 128B row

  for (int k0 = 0; k0 < NE; k0 += 64) {
#pragma unroll
    for (int i = 0; i < 4; ++i) {
      const int r = i * 32 + srow;
      const int scb = cb ^ ((r & 7) << 4);   // pre-swizzled global source col
      int am = m0 + r; if (am > BT - 1) am = BT - 1;
      gload16(A + (size_t)am * NE + k0 + (scb >> 1), &lA[r * 64 + (cb >> 1)]);
      gload16(Bw + (size_t)(n0 + r) * NE + k0 + (scb >> 1), &lB[r * 64 + (cb >> 1)]);
    }
    __syncthreads();
#pragma unroll
    for (int kk = 0; kk < 64; kk += 32) {
      bf16x8 af[4], bfr[4];
#pragma unroll
      for (int i = 0; i < 4; ++i) {
        const int ra = wm * 64 + i * 16 + l4;
        af[i] = *(const bf16x8*)&lA[(ra * 64 + kk + g * 8) ^ ((l4 & 7) << 3)];
        const int rb = wn * 64 + i * 16 + l4;
        bfr[i] = *(const bf16x8*)&lB[(rb * 64 + kk + g * 8) ^ ((l4 & 7) << 3)];
      }
#pragma unroll
      for (int i = 0; i < 4; ++i)
#pragma unroll
        for (int j = 0; j < 4; ++j)
          acc[i][j] = mfma16(af[i], bfr[j], acc[i][j]);
    }
    __syncthreads();
  }
#pragma unroll
  for (int i = 0; i < 4; ++i) {
#pragma unroll
    for (int j = 0; j < 4; ++j) {
      const int ng = n0 + wn * 64 + j * 16 + l4;
#pragma unroll
      for (int r = 0; r < 4; ++r) {
        const int m = m0 + wm * 64 + i * 16 + g * 4 + r;
        if (m < BT) {
          const float v = acc[i][j][r];
          if (MODE == 1) {
            o0[(size_t)m * NE + ng] = v;
          } else {
            if (n0 < NE)          o0[(size_t)m * NE + ng] = v;
            else if (n0 < 2 * NE) o1[(size_t)m * NE + (ng - NE)] = v;
            else                  o2[(size_t)m * NE + (ng - 2 * NE)] = f2bf(v);
          }
        }
      }
    }
  }
}

// ---------------- kernel 4: LayerNorm + axial RoPE, layout q / new-k --------
__device__ __forceinline__ void load8(const float* p, float* d) {
  float4 a = *(const float4*)p, b = *(const float4*)(p + 4);
  d[0]=a.x; d[1]=a.y; d[2]=a.z; d[3]=a.w; d[4]=b.x; d[5]=b.y; d[6]=b.z; d[7]=b.w;
}
__global__ __launch_bounds__(256) void ln_rope_k(
    const float* __restrict__ qpre, const float* __restrict__ kpre,
    const float* __restrict__ qw, const float* __restrict__ qbs,
    const float* __restrict__ kw, const float* __restrict__ kbs,
    const float* __restrict__ rc, const float* __restrict__ rs,
    u16* __restrict__ qb, u16* __restrict__ keff,
    const int* pcs, const int* pge, const int* ple) {
  const int row = blockIdx.x;       // 0..2069
  const int isk = blockIdx.y;       // 0:q 1:k
  const int tid = threadIdx.x;
  const float* src = (isk ? kpre : qpre) + (size_t)row * NE;
  float e[8];
  load8(src + tid * 8, e);
  float s = 0.f, ss = 0.f;
#pragma unroll
  for (int i = 0; i < 8; ++i) { s += e[i]; ss += e[i] * e[i]; }
#pragma unroll
  for (int mk = 32; mk >= 1; mk >>= 1) { s += __shfl_xor(s, mk); ss += __shfl_xor(ss, mk); }
  __shared__ float ps[4], pss[4];
  if ((tid & 63) == 0) { ps[tid >> 6] = s; pss[tid >> 6] = ss; }
  __syncthreads();
  s = ps[0] + ps[1] + ps[2] + ps[3];
  ss = pss[0] + pss[1] + pss[2] + pss[3];
  const float mu = s * (1.0f / NE);
  const float rstd = 1.0f / sqrtf(ss * (1.0f / NE) - mu * mu + 1e-5f);
  const int c0 = tid * 8;
  float wr[8], br[8];
  load8((isk ? kw : qw) + c0, wr);
  load8((isk ? kbs : qbs) + c0, br);
#pragma unroll
  for (int i = 0; i < 8; ++i) e[i] = (e[i] - mu) * rstd * wr[i] + br[i];
  const int b_ = row / T_TOK, t = row - b_ * T_TOK;
  if (t >= PRE) {
    const int timg = t - PRE;
    const int p0 = (c0 & 127) >> 1;     // pair index 0..60, multiple of 4
    float c4[4], s4[4];
    {
      float4 ca = *(const float4*)(rc + timg * 64 + p0);
      float4 sa = *(const float4*)(rs + timg * 64 + p0);
      c4[0]=ca.x; c4[1]=ca.y; c4[2]=ca.z; c4[3]=ca.w;
      s4[0]=sa.x; s4[1]=sa.y; s4[2]=sa.z; s4[3]=sa.w;
    }
#pragma unroll
    for (int p = 0; p < 4; ++p) {
      const float x0 = e[2*p], x1 = e[2*p+1];
      e[2*p]   = x0 * c4[p] - x1 * s4[p];
      e[2*p+1] = x0 * s4[p] + x1 * c4[p];
    }
  }
  uint4 o;
  o.x = pack2(e[0], e[1]); o.y = pack2(e[2], e[3]);
  o.z = pack2(e[4], e[5]); o.w = pack2(e[6], e[7]);
  const int h = c0 >> 7, d0 = c0 & 127;
  if (!isk) {
    *(uint4*)(qb + ((size_t)(b_ * NH + h) * T_TOK + t) * HD + d0) = o;
  } else {
    const CacheMap cm = cache_map(*pcs, *pge, *ple);
    const int jrow = cm.pos_new + t - cm.cache_start;
    if (jrow >= 0 && jrow < cm.klen)
      *(uint4*)(keff + ((size_t)(b_ * NH + h) * KPAD + jrow) * HD + d0) = o;
  }
}

// ---------------- kernel 5: gather cache_k slice -> K_eff bf16 --------------
// also zero-fills the pad rows [klen, KPAD) so the last attention tile never
// reads poison memory.
__global__ __launch_bounds__(256) void gather_k_k(
    const float* __restrict__ cache_k, u16* __restrict__ keff,
    const int* pcs, const int* pge, const int* ple) {
  const CacheMap cm = cache_map(*pcs, *pge, *ple);
  const int b = blockIdx.z, h = blockIdx.y;
  const int j = blockIdx.x * 16 + (threadIdx.x >> 4);
  const int d0 = (threadIdx.x & 15) * 8;
  if (j >= KPAD) return;
  if (j >= cm.klen) {                 // pad rows: write zeros (finite)
    uint4 z = {0, 0, 0, 0};
    *(uint4*)(keff + ((size_t)(b * NH + h) * KPAD + j) * HD + d0) = z;
    return;
  }
  const int s = eff_src(cm, cm.cache_start + j);
  if (s < 0) return;  // new tokens written by ln_rope_k
  const float* src = cache_k + (((size_t)b * CACHE_SZ + s) * NH + h) * HD + d0;
  float4 a = *(const float4*)src, c = *(const float4*)(src + 4);
  uint4 o;
  o.x = pack2(a.x, a.y); o.y = pack2(a.z, a.w);
  o.z = pack2(c.x, c.y); o.w = pack2(c.z, c.w);
  *(uint4*)(keff + ((size_t)(b * NH + h) * KPAD + j) * HD + d0) = o;
}

// ---------------- kernel 6: build V^T (D x KPAD) bf16 -----------------------
__global__ __launch_bounds__(256) void vt_fill_k(
    const float* __restrict__ cache_v, const u16* __restrict__ vtmp,
    u16* __restrict__ vt, const int* pcs, const int* pge, const int* ple) {
  const CacheMap cm = cache_map(*pcs, *pge, *ple);
  const int b = blockIdx.z, h = blockIdx.y;
  const int j0 = blockIdx.x * 64;
  const int tid = threadIdx.x;
  __shared__ u16 tile[128][72];
#pragma unroll
  for (int rd = 0; rd < 8; ++rd) {
    const int jt = rd * 8 + (tid >> 5);
    const int d0 = (tid & 31) * 4;
    const int j = j0 + jt;
    u16 r0 = 0, r1 = 0, r2 = 0, r3 = 0;    // pad cols MUST be finite (0)
    if (j < cm.klen) {
      const int s = eff_src(cm, cm.cache_start + j);
      if (s >= 0) {
        float4 a = *(const float4*)(cache_v + (((size_t)b * CACHE_SZ + s) * NH + h) * HD + d0);
        r0 = f2bf(a.x); r1 = f2bf(a.y); r2 = f2bf(a.z); r3 = f2bf(a.w);
      } else {
        const int t = -1 - s;
        const u16* p = vtmp + ((size_t)(b * T_TOK + t)) * NE + h * HD + d0;
        r0 = p[0]; r1 = p[1]; r2 = p[2]; r3 = p[3];
      }
    }
    tile[d0 + 0][jt] = r0; tile[d0 + 1][jt] = r1;
    tile[d0 + 2][jt] = r2; tile[d0 + 3][jt] = r3;
  }
  __syncthreads();
  const int drow = tid >> 1;
  const int half = tid & 1;
  u16* dst = vt + ((size_t)(b * NH + h) * HD + drow) * KPAD + j0 + half * 32;
#pragma unroll
  for (int k = 0; k < 4; ++k)
    *(uint4*)(dst + k * 8) = *(const uint4*)&tile[drow][half * 32 + k * 8];
}

// ---------------- kernel 7: flash attention ---------------------------------
// 4 waves x 16 q-rows, KV tile 64, online softmax, P via padded LDS, y^T MFMA.
__global__ __launch_bounds__(256) void attn_k(
    const u16* __restrict__ qb, const u16* __restrict__ keff,
    const u16* __restrict__ vt, u16* __restrict__ yb,
    const int* pcs, const int* pge, const int* ple) {
  const CacheMap cm = cache_map(*pcs, *pge, *ple);
  const int klen = cm.klen;
  const int b = blockIdx.z, h = blockIdx.y;
  const int tid = threadIdx.x;
  const int lane = tid & 63, wid = tid >> 6;
  const int l4 = lane & 15, g = lane >> 4;
  const int q0 = blockIdx.x * 64 + wid * 16;
  const int qrow = q0 + l4;

  __shared__ u16 p_lds[4][16][72];
  __shared__ u16 y_lds[4][16][128];
  __shared__ float alpha_w[4][16];
  __shared__ float sden_w[4][16];

  bf16x8 qf[4] = {};
  if (qrow < T_TOK) {
    const u16* qp = qb + ((size_t)(b * NH + h) * T_TOK + qrow) * HD;
#pragma unroll
    for (int c = 0; c < 4; ++c) qf[c] = *(const bf16x8*)(qp + c * 32 + g * 8);
  }
  f32x4 acc[8] = {};
  float m_r[4] = {-INFINITY, -INFINITY, -INFINITY, -INFINITY};
  float s_r[4] = {0.f, 0.f, 0.f, 0.f};
  const u16* kb = keff + (size_t)(b * NH + h) * KPAD * HD;
  const u16* vb = vt + (size_t)(b * NH + h) * HD * KPAD;
  const float SC = 0.08838834764831845f;  // 1/sqrt(128)

  for (int kv0 = 0; kv0 < klen; kv0 += 64) {
    f32x4 sf[4] = {};
#pragma unroll
    for (int f = 0; f < 4; ++f) {
      const u16* kr = kb + (size_t)(kv0 + f * 16 + l4) * HD + g * 8;
#pragma unroll
      for (int c = 0; c < 4; ++c)
        sf[f] = mfma16(qf[c], *(const bf16x8*)(kr + c * 32), sf[f]);
    }
    float tm[4], al[4], ts[4];
#pragma unroll
    for (int r = 0; r < 4; ++r) {
      float mx = -INFINITY;
#pragma unroll
      for (int f = 0; f < 4; ++f) {
        const int j = kv0 + f * 16 + l4;
        const float v = (j < klen) ? sf[f][r] * SC : -INFINITY;
        sf[f][r] = v;
        mx = fmaxf(mx, v);
      }
      tm[r] = mx;
    }
#pragma unroll
    for (int mk = 8; mk >= 1; mk >>= 1)
#pragma unroll
      for (int r = 0; r < 4; ++r) tm[r] = fmaxf(tm[r], __shfl_xor(tm[r], mk));
#pragma unroll
    for (int r = 0; r < 4; ++r) {
      const float mn = fmaxf(m_r[r], tm[r]);
      al[r] = __expf(m_r[r] - mn);
      m_r[r] = mn;
      float sum = 0.f;
#pragma unroll
      for (int f = 0; f < 4; ++f) {
        const float p = __expf(sf[f][r] - mn);
        sf[f][r] = p;
        sum += p;
      }
      ts[r] = sum;
    }
#pragma unroll
    for (int mk = 8; mk >= 1; mk >>= 1)
#pragma unroll
      for (int r = 0; r < 4; ++r) ts[r] += __shfl_xor(ts[r], mk);
#pragma unroll
    for (int r = 0; r < 4; ++r) s_r[r] = s_r[r] * al[r] + ts[r];
    if (l4 == 0) {
#pragma unroll
      for (int r = 0; r < 4; ++r) alpha_w[wid][g * 4 + r] = al[r];
    }
#pragma unroll
    for (int r = 0; r < 4; ++r)
#pragma unroll
      for (int f = 0; f < 4; ++f)
        p_lds[wid][g * 4 + r][f * 16 + l4] = f2bf(sf[f][r]);
    const float af = alpha_w[wid][l4];     // rescale factor for col t = l4
#pragma unroll
    for (int d = 0; d < 8; ++d)
#pragma unroll
      for (int r = 0; r < 4; ++r) acc[d][r] *= af;
    const bf16x8 pf0 = *(const bf16x8*)&p_lds[wid][l4][g * 8];
    const bf16x8 pf1 = *(const bf16x8*)&p_lds[wid][l4][32 + g * 8];
#pragma unroll
    for (int d = 0; d < 8; ++d) {
      const u16* vr = vb + (size_t)(d * 16 + l4) * KPAD + kv0 + g * 8;
      acc[d] = mfma16(*(const bf16x8*)vr, pf0, acc[d]);
      acc[d] = mfma16(*(const bf16x8*)(vr + 32), pf1, acc[d]);
    }
  }
  if (l4 == 0) {
#pragma unroll
    for (int r = 0; r < 4; ++r) sden_w[wid][g * 4 + r] = s_r[r];
  }
  const float inv = 1.0f / sden_w[wid][l4];
#pragma unroll
  for (int d = 0; d < 8; ++d)
#pragma unroll
    for (int r = 0; r < 4; ++r)
      y_lds[wid][l4][d * 16 + g * 4 + r] = f2bf(acc[d][r] * inv);
  const int tl = lane >> 2;
  const int ob = (lane & 3) * 32;
  const int t = q0 + tl;
  if (t < T_TOK) {
    u16* dst = yb + ((size_t)(b * T_TOK + t)) * NE + h * HD + ob;
#pragma unroll
    for (int k = 0; k < 4; ++k)
      *(uint4*)(dst + k * 8) = *(const uint4*)&y_lds[wid][tl][ob + k * 8];
  }
}

// ---------------- launcher ---------------------------------------------------
// ws layout (bytes), total ~170.1 MB (assumes ws_size >= that):
//   0        rope_cos (256KB) | 262144 rope_sin | 524288 x_bf16 (8.48MB)
//   9003008  W_bf16 [Wq|Wk|Wv|Wproj] (33.55MB) | 42557440 qpre f32 (16.96MB)
//   59514880 kpre f32 | 76472320 vtmp bf16 (8.48MB) | 84951040 q_bf16
//   93429760 K_eff bf16 B*H*KPAD*HD (34.08MB) | 127508480 V^T bf16 (34.08MB)
//   161587200 y_bf16 (8.48MB) -> end 170065920
extern "C" void kernel_launch(void* const* d_in, const int* in_sizes, int n_in,
                              void* d_out, int out_size, void* d_ws, size_t ws_size,
                              hipStream_t stream) {
  (void)in_sizes; (void)n_in; (void)out_size; (void)ws_size;
  const float* x   = (const float*)d_in[0];
  const float* Wq  = (const float*)d_in[1];
  const float* Wk  = (const float*)d_in[2];
  const float* Wv  = (const float*)d_in[3];
  const float* Wp  = (const float*)d_in[4];
  const float* qnw = (const float*)d_in[5];
  const float* qnb = (const float*)d_in[6];
  const float* knw = (const float*)d_in[7];
  const float* knb = (const float*)d_in[8];
  const float* ck  = (const float*)d_in[9];
  const float* cv  = (const float*)d_in[10];
  const int* pcs = (const int*)d_in[11];
  const int* pge = (const int*)d_in[12];
  const int* ple = (const int*)d_in[13];
  float* out = (float*)d_out;
  char* w = (char*)d_ws;

  float* rc   = (float*)(w + 0);
  float* rs   = (float*)(w + 262144);
  u16* xb     = (u16*)(w + 524288);
  u16* wb     = (u16*)(w + 9003008);
  float* qpre = (float*)(w + 42557440);
  float* kpre = (float*)(w + 59514880);
  u16* vtmp   = (u16*)(w + 76472320);
  u16* qbuf   = (u16*)(w + 84951040);
  u16* keff   = (u16*)(w + 93429760);
  u16* vtb    = (u16*)(w + 127508480);
  u16* yb     = (u16*)(w + 161587200);

  conv_bf16<<<10262, 256, 0, stream>>>(x, Wq, Wk, Wv, Wp, xb, wb);
  rope_tab_k<<<256, 256, 0, stream>>>(rc, rs);
  gemm_k<0><<<dim3(17, 48), 256, 0, stream>>>(xb, wb, qpre, kpre, vtmp);
  ln_rope_k<<<dim3(BT, 2), 256, 0, stream>>>(qpre, kpre, qnw, qnb, knw, knb,
                                             rc, rs, qbuf, keff, pcs, pge, ple);
  gather_k_k<<<dim3(260, NH, 2), 256, 0, stream>>>(ck, keff, pcs, pge, ple);
  vt_fill_k<<<dim3(65, NH, 2), 256, 0, stream>>>(cv, vtmp, vtb, pcs, pge, ple);
  attn_k<<<dim3(17, NH, 2), 256, 0, stream>>>(qbuf, keff, vtb, yb, pcs, pge, ple);
  gemm_k<1><<<dim3(17, 16), 256, 0, stream>>>(yb, wb + (size_t)3 * WN, out,
                                              nullptr, nullptr);
}

// Round 6
// 933.846 us; speedup vs baseline: 1.1808x; 1.1808x over previous
//
#include <hip/hip_runtime.h>
#include <hip/hip_bf16.h>
#include <cstdint>
#include <cstddef>
#include <math.h>

// ---------------- problem constants ----------------
#define T_TOK 1035      // TOTAL_TOKENS
#define BT    2070      // B*T
#define NE    2048      // n_embd
#define NH    16
#define HD    128
#define CACHE_SZ 5175
#define SINK  1035
#define MAXA  4140      // LOCAL_ATTN_SIZE*TOTAL_TOKENS
#define KPAD  4160      // MAXA rounded up to 64
#define PRE   11        // POSE+YAW
#define WN    4194304   // 2048*2048
#define XN    4239360   // 2070*2048

typedef unsigned short u16;
typedef __attribute__((ext_vector_type(8))) short bf16x8;
typedef __attribute__((ext_vector_type(4))) float f32x4;

__device__ __forceinline__ u16 f2bf(float f) {
  union { float f; uint32_t u; } v; v.f = f;
  return (u16)((v.u + 0x7FFFu + ((v.u >> 16) & 1)) >> 16);
}
__device__ __forceinline__ uint32_t pack2(float a, float b) {
  return (uint32_t)f2bf(a) | ((uint32_t)f2bf(b) << 16);
}

typedef __attribute__((address_space(1))) const void gvoid;
typedef __attribute__((address_space(3))) void lvoid;
__device__ __forceinline__ void gload16(const void* g, void* l) {
  __builtin_amdgcn_global_load_lds((gvoid*)g, (lvoid*)l, 16, 0, 0);
}
__device__ __forceinline__ f32x4 mfma16(bf16x8 a, bf16x8 b, f32x4 c) {
  return __builtin_amdgcn_mfma_f32_16x16x32_bf16(a, b, c, 0, 0, 0);
}

// ---------------- cache-window arithmetic (device, from runtime scalars) ----
struct CacheMap {
  int cache_start, klen, pos_new;   // pos_new: eff-index where new tokens begin
  int num_evicted, num_rolled;
  bool evict;
};
__device__ __forceinline__ CacheMap cache_map(int cs, int ge, int le) {
  CacheMap m;
  const int ce = cs + T_TOK;
  m.evict = (ce > ge) && (T_TOK + le > CACHE_SZ);
  int nle;
  if (m.evict) {
    m.num_evicted = T_TOK + le - CACHE_SZ;
    m.num_rolled  = le - m.num_evicted - SINK;
    nle = le + (ce - ge) - m.num_evicted;
    m.pos_new = SINK + m.num_rolled;
  } else {
    m.num_evicted = 0; m.num_rolled = 0;
    nle = le + (ce - ge);
    m.pos_new = nle - T_TOK;
  }
  int csrt = nle - MAXA; if (csrt < 0) csrt = 0;
  m.cache_start = csrt;
  m.klen = nle - csrt;
  return m;
}
// eff index -> cache token index (>=0) or new-token t encoded as -1-t
__device__ __forceinline__ int eff_src(const CacheMap& m, int e) {
  if (m.evict) {
    if (e < SINK) return e;
    if (e < m.pos_new) return e + m.num_evicted;
    return -1 - (e - m.pos_new);
  } else {
    if (e < m.pos_new) return e;
    return -1 - (e - m.pos_new);
  }
}

// ---------------- kernel 1: f32 -> bf16 convert (x + 4 weights) -------------
__global__ __launch_bounds__(256) void conv_bf16(
    const float* __restrict__ x, const float* __restrict__ wq,
    const float* __restrict__ wk, const float* __restrict__ wv,
    const float* __restrict__ wp, u16* __restrict__ xb, u16* __restrict__ wb) {
  const size_t i8 = ((size_t)blockIdx.x * 256 + threadIdx.x) * 8;
  if (i8 >= (size_t)XN + 4ull * WN) return;
  const float* src; u16* dst;
  if (i8 < XN) { src = x + i8; dst = xb + i8; }
  else {
    const size_t w = i8 - XN;
    const int m = (int)(w >> 22);
    const size_t o = w & (WN - 1);
    src = (m == 0 ? wq : m == 1 ? wk : m == 2 ? wv : wp) + o;
    dst = wb + w;
  }
  float4 a = *(const float4*)src;
  float4 c = *(const float4*)(src + 4);
  uint4 o;
  o.x = pack2(a.x, a.y); o.y = pack2(a.z, a.w);
  o.z = pack2(c.x, c.y); o.w = pack2(c.z, c.w);
  *(uint4*)dst = o;
}

// ---------------- kernel 2: axial RoPE tables [1024][64] --------------------
__global__ __launch_bounds__(256) void rope_tab_k(float* __restrict__ rc,
                                                  float* __restrict__ rs) {
  const int idx = blockIdx.x * 256 + threadIdx.x;   // 65536 entries
  const int t = idx >> 6, p = idx & 63;
  const int fi = p & 31;
  const float pos = (p < 32) ? (float)(t & 31) : (float)(t >> 5);
  const float freq = exp2f(-(float)fi * 0.31143075889569023f); // log2(1000)/32
  const float ang = pos * freq;
  rc[idx] = cosf(ang);
  rs[idx] = sinf(ang);
}

// ---------------- kernel 3/8: bf16 GEMM, C = A @ Bw^T (NT) ------------------
// MODE 0: A=x_bf16 (2070x2048), Bw = [Wq;Wk;Wv] (6144x2048) -> qpre/kpre f32, vtmp bf16
// MODE 1: A=y_bf16, Bw = Wproj -> out f32
template<int MODE>
__global__ __launch_bounds__(256) void gemm_k(const u16* __restrict__ A,
                                              const u16* __restrict__ Bw,
                                              float* __restrict__ o0,
                                              float* __restrict__ o1,
                                              u16* __restrict__ o2) {
  __shared__ u16 lA[128 * 64];
  __shared__ u16 lB[128 * 64];
  const int tid = threadIdx.x;
  const int m0 = blockIdx.x * 128;
  const int n0 = blockIdx.y * 128;
  const int lane = tid & 63, wid = tid >> 6;
  const int l4 = lane & 15, g = lane >> 4;
  const int wm = wid >> 1, wn = wid & 1;

  f32x4 acc[4][4] = {};

  const int srow = tid >> 3;          // 0..31
  const int cb = (tid & 7) * 16;      // byte col in 128B row

  for (int k0 = 0; k0 < NE; k0 += 64) {
#pragma unroll
    for (int i = 0; i < 4; ++i) {
      const int r = i * 32 + srow;
      const int scb = cb ^ ((r & 7) << 4);   // pre-swizzled global source col
      int am = m0 + r; if (am > BT - 1) am = BT - 1;
      gload16(A + (size_t)am * NE + k0 + (scb >> 1), &lA[r * 64 + (cb >> 1)]);
      gload16(Bw + (size_t)(n0 + r) * NE + k0 + (scb >> 1), &lB[r * 64 + (cb >> 1)]);
    }
    __syncthreads();
#pragma unroll
    for (int kk = 0; kk < 64; kk += 32) {
      bf16x8 af[4], bfr[4];
#pragma unroll
      for (int i = 0; i < 4; ++i) {
        const int ra = wm * 64 + i * 16 + l4;
        af[i] = *(const bf16x8*)&lA[(ra * 64 + kk + g * 8) ^ ((l4 & 7) << 3)];
        const int rb = wn * 64 + i * 16 + l4;
        bfr[i] = *(const bf16x8*)&lB[(rb * 64 + kk + g * 8) ^ ((l4 & 7) << 3)];
      }
#pragma unroll
      for (int i = 0; i < 4; ++i)
#pragma unroll
        for (int j = 0; j < 4; ++j)
          acc[i][j] = mfma16(af[i], bfr[j], acc[i][j]);
    }
    __syncthreads();
  }
#pragma unroll
  for (int i = 0; i < 4; ++i) {
#pragma unroll
    for (int j = 0; j < 4; ++j) {
      const int ng = n0 + wn * 64 + j * 16 + l4;
#pragma unroll
      for (int r = 0; r < 4; ++r) {
        const int m = m0 + wm * 64 + i * 16 + g * 4 + r;
        if (m < BT) {
          const float v = acc[i][j][r];
          if (MODE == 1) {
            o0[(size_t)m * NE + ng] = v;
          } else {
            if (n0 < NE)          o0[(size_t)m * NE + ng] = v;
            else if (n0 < 2 * NE) o1[(size_t)m * NE + (ng - NE)] = v;
            else                  o2[(size_t)m * NE + (ng - 2 * NE)] = f2bf(v);
          }
        }
      }
    }
  }
}

// ---------------- kernel 4: LayerNorm + axial RoPE, layout q / new-k --------
__device__ __forceinline__ void load8(const float* p, float* d) {
  float4 a = *(const float4*)p, b = *(const float4*)(p + 4);
  d[0]=a.x; d[1]=a.y; d[2]=a.z; d[3]=a.w; d[4]=b.x; d[5]=b.y; d[6]=b.z; d[7]=b.w;
}
__global__ __launch_bounds__(256) void ln_rope_k(
    const float* __restrict__ qpre, const float* __restrict__ kpre,
    const float* __restrict__ qw, const float* __restrict__ qbs,
    const float* __restrict__ kw, const float* __restrict__ kbs,
    const float* __restrict__ rc, const float* __restrict__ rs,
    u16* __restrict__ qb, u16* __restrict__ keff,
    const int* pcs, const int* pge, const int* ple) {
  const int row = blockIdx.x;       // 0..2069
  const int isk = blockIdx.y;       // 0:q 1:k
  const int tid = threadIdx.x;
  const float* src = (isk ? kpre : qpre) + (size_t)row * NE;
  float e[8];
  load8(src + tid * 8, e);
  float s = 0.f, ss = 0.f;
#pragma unroll
  for (int i = 0; i < 8; ++i) { s += e[i]; ss += e[i] * e[i]; }
#pragma unroll
  for (int mk = 32; mk >= 1; mk >>= 1) { s += __shfl_xor(s, mk); ss += __shfl_xor(ss, mk); }
  __shared__ float ps[4], pss[4];
  if ((tid & 63) == 0) { ps[tid >> 6] = s; pss[tid >> 6] = ss; }
  __syncthreads();
  s = ps[0] + ps[1] + ps[2] + ps[3];
  ss = pss[0] + pss[1] + pss[2] + pss[3];
  const float mu = s * (1.0f / NE);
  const float rstd = 1.0f / sqrtf(ss * (1.0f / NE) - mu * mu + 1e-5f);
  const int c0 = tid * 8;
  float wr[8], br[8];
  load8((isk ? kw : qw) + c0, wr);
  load8((isk ? kbs : qbs) + c0, br);
#pragma unroll
  for (int i = 0; i < 8; ++i) e[i] = (e[i] - mu) * rstd * wr[i] + br[i];
  const int b_ = row / T_TOK, t = row - b_ * T_TOK;
  if (t >= PRE) {
    const int timg = t - PRE;
    const int p0 = (c0 & 127) >> 1;     // pair index 0..60, multiple of 4
    float c4[4], s4[4];
    {
      float4 ca = *(const float4*)(rc + timg * 64 + p0);
      float4 sa = *(const float4*)(rs + timg * 64 + p0);
      c4[0]=ca.x; c4[1]=ca.y; c4[2]=ca.z; c4[3]=ca.w;
      s4[0]=sa.x; s4[1]=sa.y; s4[2]=sa.z; s4[3]=sa.w;
    }
#pragma unroll
    for (int p = 0; p < 4; ++p) {
      const float x0 = e[2*p], x1 = e[2*p+1];
      e[2*p]   = x0 * c4[p] - x1 * s4[p];
      e[2*p+1] = x0 * s4[p] + x1 * c4[p];
    }
  }
  uint4 o;
  o.x = pack2(e[0], e[1]); o.y = pack2(e[2], e[3]);
  o.z = pack2(e[4], e[5]); o.w = pack2(e[6], e[7]);
  const int h = c0 >> 7, d0 = c0 & 127;
  if (!isk) {
    *(uint4*)(qb + ((size_t)(b_ * NH + h) * T_TOK + t) * HD + d0) = o;
  } else {
    const CacheMap cm = cache_map(*pcs, *pge, *ple);
    const int jrow = cm.pos_new + t - cm.cache_start;
    if (jrow >= 0 && jrow < cm.klen)
      *(uint4*)(keff + ((size_t)(b_ * NH + h) * KPAD + jrow) * HD + d0) = o;
  }
}

// ---------------- kernel 5: gather cache_k slice -> K_eff bf16 --------------
// also zero-fills the pad rows [klen, KPAD) so the last attention tile never
// reads poison memory.
__global__ __launch_bounds__(256) void gather_k_k(
    const float* __restrict__ cache_k, u16* __restrict__ keff,
    const int* pcs, const int* pge, const int* ple) {
  const CacheMap cm = cache_map(*pcs, *pge, *ple);
  const int b = blockIdx.z, h = blockIdx.y;
  const int j = blockIdx.x * 16 + (threadIdx.x >> 4);
  const int d0 = (threadIdx.x & 15) * 8;
  if (j >= KPAD) return;
  if (j >= cm.klen) {                 // pad rows: write zeros (finite)
    uint4 z = {0, 0, 0, 0};
    *(uint4*)(keff + ((size_t)(b * NH + h) * KPAD + j) * HD + d0) = z;
    return;
  }
  const int s = eff_src(cm, cm.cache_start + j);
  if (s < 0) return;  // new tokens written by ln_rope_k
  const float* src = cache_k + (((size_t)b * CACHE_SZ + s) * NH + h) * HD + d0;
  float4 a = *(const float4*)src, c = *(const float4*)(src + 4);
  uint4 o;
  o.x = pack2(a.x, a.y); o.y = pack2(a.z, a.w);
  o.z = pack2(c.x, c.y); o.w = pack2(c.z, c.w);
  *(uint4*)(keff + ((size_t)(b * NH + h) * KPAD + j) * HD + d0) = o;
}

// ---------------- kernel 6: build V^T (D x KPAD) bf16 -----------------------
__global__ __launch_bounds__(256) void vt_fill_k(
    const float* __restrict__ cache_v, const u16* __restrict__ vtmp,
    u16* __restrict__ vt, const int* pcs, const int* pge, const int* ple) {
  const CacheMap cm = cache_map(*pcs, *pge, *ple);
  const int b = blockIdx.z, h = blockIdx.y;
  const int j0 = blockIdx.x * 64;
  const int tid = threadIdx.x;
  __shared__ u16 tile[128][72];
#pragma unroll
  for (int rd = 0; rd < 8; ++rd) {
    const int jt = rd * 8 + (tid >> 5);
    const int d0 = (tid & 31) * 4;
    const int j = j0 + jt;
    u16 r0 = 0, r1 = 0, r2 = 0, r3 = 0;    // pad cols MUST be finite (0)
    if (j < cm.klen) {
      const int s = eff_src(cm, cm.cache_start + j);
      if (s >= 0) {
        float4 a = *(const float4*)(cache_v + (((size_t)b * CACHE_SZ + s) * NH + h) * HD + d0);
        r0 = f2bf(a.x); r1 = f2bf(a.y); r2 = f2bf(a.z); r3 = f2bf(a.w);
      } else {
        const int t = -1 - s;
        const u16* p = vtmp + ((size_t)(b * T_TOK + t)) * NE + h * HD + d0;
        r0 = p[0]; r1 = p[1]; r2 = p[2]; r3 = p[3];
      }
    }
    tile[d0 + 0][jt] = r0; tile[d0 + 1][jt] = r1;
    tile[d0 + 2][jt] = r2; tile[d0 + 3][jt] = r3;
  }
  __syncthreads();
  const int drow = tid >> 1;
  const int half = tid & 1;
  u16* dst = vt + ((size_t)(b * NH + h) * HD + drow) * KPAD + j0 + half * 32;
#pragma unroll
  for (int k = 0; k < 4; ++k)
    *(uint4*)(dst + k * 8) = *(const uint4*)&tile[drow][half * 32 + k * 8];
}

// ---------------- kernel 7: flash attention (KV-split across waves) ---------
// One block = 16 q-rows of one (b,h). 4 waves split the KV tiles (t%4==wid),
// each runs an independent online softmax; end-of-block combine merges
// (m,l,acc) across the 4 waves in LDS. Grid = 65*16*2 = 2080 blocks with a
// bijective XCD swizzle so same-(b,h) blocks co-locate on one XCD's L2.
__global__ __launch_bounds__(256) void attn_k(
    const u16* __restrict__ qbuf, const u16* __restrict__ keff,
    const u16* __restrict__ vt, u16* __restrict__ yb,
    const int* pcs, const int* pge, const int* ple) {
  const CacheMap cm = cache_map(*pcs, *pge, *ple);
  const int klen = cm.klen;
  const int hw = blockIdx.x;                  // 0..2079
  const int id = (hw & 7) * 260 + (hw >> 3);  // bijective XCD swizzle (2080=8*260)
  const int qb_i = id % 65;
  const int bh = id / 65;
  const int h = bh & 15, b = bh >> 4;
  const int tid = threadIdx.x;
  const int lane = tid & 63, wid = tid >> 6;
  const int l4 = lane & 15, g = lane >> 4;
  const int q0 = qb_i * 16;
  const int qrow = q0 + l4;

  // loop-phase LDS (p_lds + alpha) overlaps the post-barrier combine buffer
  __shared__ __align__(16) char smraw[4 * 16 * 132 * 4];   // 33792 B
  u16 (*p_lds)[16][72] = (u16(*)[16][72])smraw;            // 9216 B
  float (*alpha_w)[16] = (float(*)[16])(smraw + 9216);     // 256 B
  float (*accbuf)[16][132] = (float(*)[16][132])smraw;     // reuse post-barrier
  __shared__ float mw[4][16], lw[4][16];

  bf16x8 qf[4] = {};
  if (qrow < T_TOK) {
    const u16* qp = qbuf + ((size_t)(b * NH + h) * T_TOK + qrow) * HD;
#pragma unroll
    for (int c = 0; c < 4; ++c) qf[c] = *(const bf16x8*)(qp + c * 32 + g * 8);
  }
  f32x4 acc[8] = {};
  float m_r[4] = {-INFINITY, -INFINITY, -INFINITY, -INFINITY};
  float s_r[4] = {0.f, 0.f, 0.f, 0.f};
  const u16* kb = keff + (size_t)(b * NH + h) * KPAD * HD;
  const u16* vb = vt + (size_t)(b * NH + h) * HD * KPAD;
  const float SC = 0.08838834764831845f;  // 1/sqrt(128)
  const int ntile = (klen + 63) >> 6;

  for (int t = wid; t < ntile; t += 4) {
    const int kv0 = t * 64;
    f32x4 sf[4] = {};
#pragma unroll
    for (int f = 0; f < 4; ++f) {
      const u16* kr = kb + (size_t)(kv0 + f * 16 + l4) * HD + g * 8;
#pragma unroll
      for (int c = 0; c < 4; ++c)
        sf[f] = mfma16(qf[c], *(const bf16x8*)(kr + c * 32), sf[f]);
    }
    float tm[4], al[4], ts[4];
#pragma unroll
    for (int r = 0; r < 4; ++r) {
      float mx = -INFINITY;
#pragma unroll
      for (int f = 0; f < 4; ++f) {
        const int j = kv0 + f * 16 + l4;
        const float v = (j < klen) ? sf[f][r] * SC : -INFINITY;
        sf[f][r] = v;
        mx = fmaxf(mx, v);
      }
      tm[r] = mx;
    }
#pragma unroll
    for (int mk = 8; mk >= 1; mk >>= 1)
#pragma unroll
      for (int r = 0; r < 4; ++r) tm[r] = fmaxf(tm[r], __shfl_xor(tm[r], mk));
#pragma unroll
    for (int r = 0; r < 4; ++r) {
      const float mn = fmaxf(m_r[r], tm[r]);
      al[r] = __expf(m_r[r] - mn);
      m_r[r] = mn;
      float sum = 0.f;
#pragma unroll
      for (int f = 0; f < 4; ++f) {
        const float p = __expf(sf[f][r] - mn);
        sf[f][r] = p;
        sum += p;
      }
      ts[r] = sum;
    }
#pragma unroll
    for (int mk = 8; mk >= 1; mk >>= 1)
#pragma unroll
      for (int r = 0; r < 4; ++r) ts[r] += __shfl_xor(ts[r], mk);
#pragma unroll
    for (int r = 0; r < 4; ++r) s_r[r] = s_r[r] * al[r] + ts[r];
    if (l4 == 0) {
#pragma unroll
      for (int r = 0; r < 4; ++r) alpha_w[wid][g * 4 + r] = al[r];
    }
#pragma unroll
    for (int r = 0; r < 4; ++r)
#pragma unroll
      for (int f = 0; f < 4; ++f)
        p_lds[wid][g * 4 + r][f * 16 + l4] = f2bf(sf[f][r]);
    const float af = alpha_w[wid][l4];     // rescale factor for col t = l4
#pragma unroll
    for (int d = 0; d < 8; ++d)
#pragma unroll
      for (int r = 0; r < 4; ++r) acc[d][r] *= af;
    const bf16x8 pf0 = *(const bf16x8*)&p_lds[wid][l4][g * 8];
    const bf16x8 pf1 = *(const bf16x8*)&p_lds[wid][l4][32 + g * 8];
#pragma unroll
    for (int d = 0; d < 8; ++d) {
      const u16* vr = vb + (size_t)(d * 16 + l4) * KPAD + kv0 + g * 8;
      acc[d] = mfma16(*(const bf16x8*)vr, pf0, acc[d]);
      acc[d] = mfma16(*(const bf16x8*)(vr + 32), pf1, acc[d]);
    }
  }

  // ------- cross-wave combine (online-softmax merge) -------
  if (l4 == 0) {
#pragma unroll
    for (int r = 0; r < 4; ++r) { mw[wid][g * 4 + r] = m_r[r]; lw[wid][g * 4 + r] = s_r[r]; }
  }
  __syncthreads();   // all waves done with loop; p_lds/alpha now dead
  const float M4 = fmaxf(fmaxf(mw[0][l4], mw[1][l4]), fmaxf(mw[2][l4], mw[3][l4]));
  const float mysc = __expf(mw[wid][l4] - M4);   // my wave's factor for col l4
#pragma unroll
  for (int d = 0; d < 8; ++d)
#pragma unroll
    for (int r = 0; r < 4; ++r)
      accbuf[wid][l4][d * 16 + g * 4 + r] = acc[d][r] * mysc;
  __syncthreads();
  const int row = tid >> 4, col0 = (tid & 15) * 8;
  const float Mr = fmaxf(fmaxf(mw[0][row], mw[1][row]), fmaxf(mw[2][row], mw[3][row]));
  float den = 0.f;
#pragma unroll
  for (int w = 0; w < 4; ++w) den += lw[w][row] * __expf(mw[w][row] - Mr);
  const float inv = 1.0f / den;
  const int tt = q0 + row;
  if (tt < T_TOK) {
    float o[8];
#pragma unroll
    for (int c = 0; c < 8; ++c)
      o[c] = (accbuf[0][row][col0 + c] + accbuf[1][row][col0 + c] +
              accbuf[2][row][col0 + c] + accbuf[3][row][col0 + c]) * inv;
    uint4 ov;
    ov.x = pack2(o[0], o[1]); ov.y = pack2(o[2], o[3]);
    ov.z = pack2(o[4], o[5]); ov.w = pack2(o[6], o[7]);
    *(uint4*)(yb + ((size_t)(b * T_TOK + tt)) * NE + h * HD + col0) = ov;
  }
}

// ---------------- launcher ---------------------------------------------------
// ws layout (bytes), total ~170.1 MB (assumes ws_size >= that):
//   0        rope_cos (256KB) | 262144 rope_sin | 524288 x_bf16 (8.48MB)
//   9003008  W_bf16 [Wq|Wk|Wv|Wproj] (33.55MB) | 42557440 qpre f32 (16.96MB)
//   59514880 kpre f32 | 76472320 vtmp bf16 (8.48MB) | 84951040 q_bf16
//   93429760 K_eff bf16 B*H*KPAD*HD (34.08MB) | 127508480 V^T bf16 (34.08MB)
//   161587200 y_bf16 (8.48MB) -> end 170065920
extern "C" void kernel_launch(void* const* d_in, const int* in_sizes, int n_in,
                              void* d_out, int out_size, void* d_ws, size_t ws_size,
                              hipStream_t stream) {
  (void)in_sizes; (void)n_in; (void)out_size; (void)ws_size;
  const float* x   = (const float*)d_in[0];
  const float* Wq  = (const float*)d_in[1];
  const float* Wk  = (const float*)d_in[2];
  const float* Wv  = (const float*)d_in[3];
  const float* Wp  = (const float*)d_in[4];
  const float* qnw = (const float*)d_in[5];
  const float* qnb = (const float*)d_in[6];
  const float* knw = (const float*)d_in[7];
  const float* knb = (const float*)d_in[8];
  const float* ck  = (const float*)d_in[9];
  const float* cv  = (const float*)d_in[10];
  const int* pcs = (const int*)d_in[11];
  const int* pge = (const int*)d_in[12];
  const int* ple = (const int*)d_in[13];
  float* out = (float*)d_out;
  char* w = (char*)d_ws;

  float* rc   = (float*)(w + 0);
  float* rs   = (float*)(w + 262144);
  u16* xb     = (u16*)(w + 524288);
  u16* wb     = (u16*)(w + 9003008);
  float* qpre = (float*)(w + 42557440);
  float* kpre = (float*)(w + 59514880);
  u16* vtmp   = (u16*)(w + 76472320);
  u16* qbuf   = (u16*)(w + 84951040);
  u16* keff   = (u16*)(w + 93429760);
  u16* vtb    = (u16*)(w + 127508480);
  u16* yb     = (u16*)(w + 161587200);

  conv_bf16<<<10262, 256, 0, stream>>>(x, Wq, Wk, Wv, Wp, xb, wb);
  rope_tab_k<<<256, 256, 0, stream>>>(rc, rs);
  gemm_k<0><<<dim3(17, 48), 256, 0, stream>>>(xb, wb, qpre, kpre, vtmp);
  ln_rope_k<<<dim3(BT, 2), 256, 0, stream>>>(qpre, kpre, qnw, qnb, knw, knb,
                                             rc, rs, qbuf, keff, pcs, pge, ple);
  gather_k_k<<<dim3(260, NH, 2), 256, 0, stream>>>(ck, keff, pcs, pge, ple);
  vt_fill_k<<<dim3(65, NH, 2), 256, 0, stream>>>(cv, vtmp, vtb, pcs, pge, ple);
  attn_k<<<2080, 256, 0, stream>>>(qbuf, keff, vtb, yb, pcs, pge, ple);
  gemm_k<1><<<dim3(17, 16), 256, 0, stream>>>(yb, wb + (size_t)3 * WN, out,
                                              nullptr, nullptr);
}

// Round 7
// 637.231 us; speedup vs baseline: 1.7304x; 1.4655x over previous
//
#include <hip/hip_runtime.h>
#include <hip/hip_bf16.h>
#include <cstdint>
#include <cstddef>
#include <math.h>

// ---------------- problem constants ----------------
#define T_TOK 1035      // TOTAL_TOKENS
#define BT    2070      // B*T
#define NE    2048      // n_embd
#define NH    16
#define HD    128
#define CACHE_SZ 5175
#define SINK  1035
#define MAXA  4140      // LOCAL_ATTN_SIZE*TOTAL_TOKENS
#define KPAD  4160      // MAXA rounded up to 64
#define PRE   11        // POSE+YAW
#define WN    4194304   // 2048*2048
#define XN    4239360   // 2070*2048

typedef unsigned short u16;
typedef __attribute__((ext_vector_type(8))) short bf16x8;
typedef __attribute__((ext_vector_type(4))) float f32x4;

__device__ __forceinline__ u16 f2bf(float f) {
  union { float f; uint32_t u; } v; v.f = f;
  return (u16)((v.u + 0x7FFFu + ((v.u >> 16) & 1)) >> 16);
}
__device__ __forceinline__ uint32_t pack2(float a, float b) {
  return (uint32_t)f2bf(a) | ((uint32_t)f2bf(b) << 16);
}

typedef __attribute__((address_space(1))) const void gvoid;
typedef __attribute__((address_space(3))) void lvoid;
__device__ __forceinline__ void gload16(const void* g, void* l) {
  __builtin_amdgcn_global_load_lds((gvoid*)g, (lvoid*)l, 16, 0, 0);
}
__device__ __forceinline__ f32x4 mfma16(bf16x8 a, bf16x8 b, f32x4 c) {
  return __builtin_amdgcn_mfma_f32_16x16x32_bf16(a, b, c, 0, 0, 0);
}

// MFMA-native tiled layouts (u16 index within one (b,h) plane of size KPAD*HD):
// K: element (key j, dim e) -> [j>>6][(j>>4)&3][e>>5][(e>>3)&3][j&15][e&7]
__device__ __forceinline__ size_t kt_idx(int j, int e) {
  return ((size_t)(((((j >> 6) * 4 + ((j >> 4) & 3)) * 4 + (e >> 5)) * 4 +
                    ((e >> 3) & 3)))) * 128 + (j & 15) * 8 + (e & 7);
}
// V: element (key j, dim v)  -> [j>>6][v>>4][(j>>3)&7][v&15][j&7]

// ---------------- cache-window arithmetic (device, from runtime scalars) ----
struct CacheMap {
  int cache_start, klen, pos_new;   // pos_new: eff-index where new tokens begin
  int num_evicted, num_rolled;
  bool evict;
};
__device__ __forceinline__ CacheMap cache_map(int cs, int ge, int le) {
  CacheMap m;
  const int ce = cs + T_TOK;
  m.evict = (ce > ge) && (T_TOK + le > CACHE_SZ);
  int nle;
  if (m.evict) {
    m.num_evicted = T_TOK + le - CACHE_SZ;
    m.num_rolled  = le - m.num_evicted - SINK;
    nle = le + (ce - ge) - m.num_evicted;
    m.pos_new = SINK + m.num_rolled;
  } else {
    m.num_evicted = 0; m.num_rolled = 0;
    nle = le + (ce - ge);
    m.pos_new = nle - T_TOK;
  }
  int csrt = nle - MAXA; if (csrt < 0) csrt = 0;
  m.cache_start = csrt;
  m.klen = nle - csrt;
  return m;
}
// eff index -> cache token index (>=0) or new-token t encoded as -1-t
__device__ __forceinline__ int eff_src(const CacheMap& m, int e) {
  if (m.evict) {
    if (e < SINK) return e;
    if (e < m.pos_new) return e + m.num_evicted;
    return -1 - (e - m.pos_new);
  } else {
    if (e < m.pos_new) return e;
    return -1 - (e - m.pos_new);
  }
}

// ---------------- kernel 1: f32 -> bf16 convert (x + 4 weights) -------------
__global__ __launch_bounds__(256) void conv_bf16(
    const float* __restrict__ x, const float* __restrict__ wq,
    const float* __restrict__ wk, const float* __restrict__ wv,
    const float* __restrict__ wp, u16* __restrict__ xb, u16* __restrict__ wb) {
  const size_t i8 = ((size_t)blockIdx.x * 256 + threadIdx.x) * 8;
  if (i8 >= (size_t)XN + 4ull * WN) return;
  const float* src; u16* dst;
  if (i8 < XN) { src = x + i8; dst = xb + i8; }
  else {
    const size_t w = i8 - XN;
    const int m = (int)(w >> 22);
    const size_t o = w & (WN - 1);
    src = (m == 0 ? wq : m == 1 ? wk : m == 2 ? wv : wp) + o;
    dst = wb + w;
  }
  float4 a = *(const float4*)src;
  float4 c = *(const float4*)(src + 4);
  uint4 o;
  o.x = pack2(a.x, a.y); o.y = pack2(a.z, a.w);
  o.z = pack2(c.x, c.y); o.w = pack2(c.z, c.w);
  *(uint4*)dst = o;
}

// ---------------- kernel 2: axial RoPE tables [1024][64] --------------------
__global__ __launch_bounds__(256) void rope_tab_k(float* __restrict__ rc,
                                                  float* __restrict__ rs) {
  const int idx = blockIdx.x * 256 + threadIdx.x;   // 65536 entries
  const int t = idx >> 6, p = idx & 63;
  const int fi = p & 31;
  const float pos = (p < 32) ? (float)(t & 31) : (float)(t >> 5);
  const float freq = exp2f(-(float)fi * 0.31143075889569023f); // log2(1000)/32
  const float ang = pos * freq;
  rc[idx] = cosf(ang);
  rs[idx] = sinf(ang);
}

// ---------------- kernel 3/8: bf16 GEMM, C = A @ Bw^T (NT) ------------------
template<int MODE>
__global__ __launch_bounds__(256) void gemm_k(const u16* __restrict__ A,
                                              const u16* __restrict__ Bw,
                                              float* __restrict__ o0,
                                              float* __restrict__ o1,
                                              u16* __restrict__ o2) {
  __shared__ u16 lA[128 * 64];
  __shared__ u16 lB[128 * 64];
  const int tid = threadIdx.x;
  const int m0 = blockIdx.x * 128;
  const int n0 = blockIdx.y * 128;
  const int lane = tid & 63, wid = tid >> 6;
  const int l4 = lane & 15, g = lane >> 4;
  const int wm = wid >> 1, wn = wid & 1;

  f32x4 acc[4][4] = {};

  const int srow = tid >> 3;          // 0..31
  const int cb = (tid & 7) * 16;      // byte col in 128B row

  for (int k0 = 0; k0 < NE; k0 += 64) {
#pragma unroll
    for (int i = 0; i < 4; ++i) {
      const int r = i * 32 + srow;
      const int scb = cb ^ ((r & 7) << 4);   // pre-swizzled global source col
      int am = m0 + r; if (am > BT - 1) am = BT - 1;
      gload16(A + (size_t)am * NE + k0 + (scb >> 1), &lA[r * 64 + (cb >> 1)]);
      gload16(Bw + (size_t)(n0 + r) * NE + k0 + (scb >> 1), &lB[r * 64 + (cb >> 1)]);
    }
    __syncthreads();
#pragma unroll
    for (int kk = 0; kk < 64; kk += 32) {
      bf16x8 af[4], bfr[4];
#pragma unroll
      for (int i = 0; i < 4; ++i) {
        const int ra = wm * 64 + i * 16 + l4;
        af[i] = *(const bf16x8*)&lA[(ra * 64 + kk + g * 8) ^ ((l4 & 7) << 3)];
        const int rb = wn * 64 + i * 16 + l4;
        bfr[i] = *(const bf16x8*)&lB[(rb * 64 + kk + g * 8) ^ ((l4 & 7) << 3)];
      }
#pragma unroll
      for (int i = 0; i < 4; ++i)
#pragma unroll
        for (int j = 0; j < 4; ++j)
          acc[i][j] = mfma16(af[i], bfr[j], acc[i][j]);
    }
    __syncthreads();
  }
#pragma unroll
  for (int i = 0; i < 4; ++i) {
#pragma unroll
    for (int j = 0; j < 4; ++j) {
      const int ng = n0 + wn * 64 + j * 16 + l4;
#pragma unroll
      for (int r = 0; r < 4; ++r) {
        const int m = m0 + wm * 64 + i * 16 + g * 4 + r;
        if (m < BT) {
          const float v = acc[i][j][r];
          if (MODE == 1) {
            o0[(size_t)m * NE + ng] = v;
          } else {
            if (n0 < NE)          o0[(size_t)m * NE + ng] = v;
            else if (n0 < 2 * NE) o1[(size_t)m * NE + (ng - NE)] = v;
            else                  o2[(size_t)m * NE + (ng - 2 * NE)] = f2bf(v);
          }
        }
      }
    }
  }
}

// ---------------- kernel 4: LayerNorm + axial RoPE, layout q / new-k --------
__device__ __forceinline__ void load8(const float* p, float* d) {
  float4 a = *(const float4*)p, b = *(const float4*)(p + 4);
  d[0]=a.x; d[1]=a.y; d[2]=a.z; d[3]=a.w; d[4]=b.x; d[5]=b.y; d[6]=b.z; d[7]=b.w;
}
__global__ __launch_bounds__(256) void ln_rope_k(
    const float* __restrict__ qpre, const float* __restrict__ kpre,
    const float* __restrict__ qw, const float* __restrict__ qbs,
    const float* __restrict__ kw, const float* __restrict__ kbs,
    const float* __restrict__ rc, const float* __restrict__ rs,
    u16* __restrict__ qb, u16* __restrict__ keff,
    const int* pcs, const int* pge, const int* ple) {
  const int row = blockIdx.x;       // 0..2069
  const int isk = blockIdx.y;       // 0:q 1:k
  const int tid = threadIdx.x;
  const float* src = (isk ? kpre : qpre) + (size_t)row * NE;
  float e[8];
  load8(src + tid * 8, e);
  float s = 0.f, ss = 0.f;
#pragma unroll
  for (int i = 0; i < 8; ++i) { s += e[i]; ss += e[i] * e[i]; }
#pragma unroll
  for (int mk = 32; mk >= 1; mk >>= 1) { s += __shfl_xor(s, mk); ss += __shfl_xor(ss, mk); }
  __shared__ float ps[4], pss[4];
  if ((tid & 63) == 0) { ps[tid >> 6] = s; pss[tid >> 6] = ss; }
  __syncthreads();
  s = ps[0] + ps[1] + ps[2] + ps[3];
  ss = pss[0] + pss[1] + pss[2] + pss[3];
  const float mu = s * (1.0f / NE);
  const float rstd = 1.0f / sqrtf(ss * (1.0f / NE) - mu * mu + 1e-5f);
  const int c0 = tid * 8;
  float wr[8], br[8];
  load8((isk ? kw : qw) + c0, wr);
  load8((isk ? kbs : qbs) + c0, br);
#pragma unroll
  for (int i = 0; i < 8; ++i) e[i] = (e[i] - mu) * rstd * wr[i] + br[i];
  const int b_ = row / T_TOK, t = row - b_ * T_TOK;
  if (t >= PRE) {
    const int timg = t - PRE;
    const int p0 = (c0 & 127) >> 1;     // pair index 0..60, multiple of 4
    float c4[4], s4[4];
    {
      float4 ca = *(const float4*)(rc + timg * 64 + p0);
      float4 sa = *(const float4*)(rs + timg * 64 + p0);
      c4[0]=ca.x; c4[1]=ca.y; c4[2]=ca.z; c4[3]=ca.w;
      s4[0]=sa.x; s4[1]=sa.y; s4[2]=sa.z; s4[3]=sa.w;
    }
#pragma unroll
    for (int p = 0; p < 4; ++p) {
      const float x0 = e[2*p], x1 = e[2*p+1];
      e[2*p]   = x0 * c4[p] - x1 * s4[p];
      e[2*p+1] = x0 * s4[p] + x1 * c4[p];
    }
  }
  uint4 o;
  o.x = pack2(e[0], e[1]); o.y = pack2(e[2], e[3]);
  o.z = pack2(e[4], e[5]); o.w = pack2(e[6], e[7]);
  const int h = c0 >> 7, d0 = c0 & 127;
  if (!isk) {
    *(uint4*)(qb + ((size_t)(b_ * NH + h) * T_TOK + t) * HD + d0) = o;
  } else {
    const CacheMap cm = cache_map(*pcs, *pge, *ple);
    const int jrow = cm.pos_new + t - cm.cache_start;
    if (jrow >= 0 && jrow < cm.klen)
      *(uint4*)(keff + (size_t)(b_ * NH + h) * (KPAD * HD) + kt_idx(jrow, d0)) = o;
  }
}

// ---------------- kernel 5: gather cache_k slice -> K_eff (tiled) -----------
// also zero-fills pad rows [klen, KPAD) so the last tile never reads poison.
__global__ __launch_bounds__(256) void gather_k_k(
    const float* __restrict__ cache_k, u16* __restrict__ keff,
    const int* pcs, const int* pge, const int* ple) {
  const CacheMap cm = cache_map(*pcs, *pge, *ple);
  const int b = blockIdx.z, h = blockIdx.y;
  const int j = blockIdx.x * 16 + (threadIdx.x >> 4);
  const int d0 = (threadIdx.x & 15) * 8;
  if (j >= KPAD) return;
  u16* dst = keff + (size_t)(b * NH + h) * (KPAD * HD) + kt_idx(j, d0);
  if (j >= cm.klen) {                 // pad rows: write zeros (finite)
    uint4 z = {0, 0, 0, 0};
    *(uint4*)dst = z;
    return;
  }
  const int s = eff_src(cm, cm.cache_start + j);
  if (s < 0) return;  // new tokens written by ln_rope_k
  const float* src = cache_k + (((size_t)b * CACHE_SZ + s) * NH + h) * HD + d0;
  float4 a = *(const float4*)src, c = *(const float4*)(src + 4);
  uint4 o;
  o.x = pack2(a.x, a.y); o.y = pack2(a.z, a.w);
  o.z = pack2(c.x, c.y); o.w = pack2(c.z, c.w);
  *(uint4*)dst = o;
}

// ---------------- kernel 6: build V (tiled MFMA-native) ---------------------
__global__ __launch_bounds__(256) void vt_fill_k(
    const float* __restrict__ cache_v, const u16* __restrict__ vtmp,
    u16* __restrict__ vt, const int* pcs, const int* pge, const int* ple) {
  const CacheMap cm = cache_map(*pcs, *pge, *ple);
  const int b = blockIdx.z, h = blockIdx.y;
  const int tile = blockIdx.x;
  const int j0 = tile * 64;
  const int tid = threadIdx.x;
  __shared__ u16 tbuf[128][72];    // [v][j_in_tile]
#pragma unroll
  for (int rd = 0; rd < 8; ++rd) {
    const int jt = rd * 8 + (tid >> 5);
    const int d0 = (tid & 31) * 4;
    const int j = j0 + jt;
    u16 r0 = 0, r1 = 0, r2 = 0, r3 = 0;    // pad cols MUST be finite (0)
    if (j < cm.klen) {
      const int s = eff_src(cm, cm.cache_start + j);
      if (s >= 0) {
        float4 a = *(const float4*)(cache_v + (((size_t)b * CACHE_SZ + s) * NH + h) * HD + d0);
        r0 = f2bf(a.x); r1 = f2bf(a.y); r2 = f2bf(a.z); r3 = f2bf(a.w);
      } else {
        const int t = -1 - s;
        const u16* p = vtmp + ((size_t)(b * T_TOK + t)) * NE + h * HD + d0;
        r0 = p[0]; r1 = p[1]; r2 = p[2]; r3 = p[3];
      }
    }
    tbuf[d0 + 0][jt] = r0; tbuf[d0 + 1][jt] = r1;
    tbuf[d0 + 2][jt] = r2; tbuf[d0 + 3][jt] = r3;
  }
  __syncthreads();
  // write tiled: [d(8)][cc(8)][l4(16)][8elem] — 1024 uint4 per tile
  u16* base = vt + (size_t)(b * NH + h) * (KPAD * HD) + (size_t)tile * 8192;
#pragma unroll
  for (int k = 0; k < 4; ++k) {
    const int o = k * 256 + tid;
    const int d = o >> 7, cc = (o >> 4) & 7, lv = o & 15;
    *(uint4*)(base + (size_t)o * 8) = *(const uint4*)&tbuf[d * 16 + lv][cc * 8];
  }
}

// ---------------- kernel 7: flash attention (KV-split across waves) ---------
// One block = 16 q-rows of one (b,h). 4 waves split the KV tiles (t%4==wid),
// each runs an independent online softmax; end-of-block combine merges
// (m,l,acc) across the 4 waves in LDS. All K/V fragment loads are contiguous
// 1KB wave bursts (base + lane*16B) thanks to the tiled layouts.
__global__ __launch_bounds__(256) void attn_k(
    const u16* __restrict__ qbuf, const u16* __restrict__ keff,
    const u16* __restrict__ vt, u16* __restrict__ yb,
    const int* pcs, const int* pge, const int* ple) {
  const CacheMap cm = cache_map(*pcs, *pge, *ple);
  const int klen = cm.klen;
  const int hw = blockIdx.x;                  // 0..2079
  const int id = (hw & 7) * 260 + (hw >> 3);  // bijective XCD swizzle (2080=8*260)
  const int qb_i = id % 65;
  const int bh = id / 65;
  const int h = bh & 15, b = bh >> 4;
  const int tid = threadIdx.x;
  const int lane = tid & 63, wid = tid >> 6;
  const int l4 = lane & 15, g = lane >> 4;
  const int q0 = qb_i * 16;
  const int qrow = q0 + l4;
  const int lane8 = lane * 8;

  // loop-phase LDS (p_lds + alpha) overlaps the post-barrier combine buffer
  __shared__ __align__(16) char smraw[4 * 16 * 132 * 4];   // 33792 B
  u16 (*p_lds)[16][72] = (u16(*)[16][72])smraw;            // 9216 B
  float (*alpha_w)[16] = (float(*)[16])(smraw + 9216);     // 256 B
  float (*accbuf)[16][132] = (float(*)[16][132])smraw;     // reuse post-barrier
  __shared__ float mw[4][16], lw[4][16];

  bf16x8 qf[4] = {};
  if (qrow < T_TOK) {
    const u16* qp = qbuf + ((size_t)(b * NH + h) * T_TOK + qrow) * HD;
#pragma unroll
    for (int c = 0; c < 4; ++c) qf[c] = *(const bf16x8*)(qp + c * 32 + g * 8);
  }
  f32x4 acc[8] = {};
  float m_r[4] = {-INFINITY, -INFINITY, -INFINITY, -INFINITY};
  float s_r[4] = {0.f, 0.f, 0.f, 0.f};
  const u16* kb = keff + (size_t)(b * NH + h) * (KPAD * HD);
  const u16* vb = vt + (size_t)(b * NH + h) * (KPAD * HD);
  const float SC = 0.08838834764831845f;  // 1/sqrt(128)
  const int ntile = (klen + 63) >> 6;

  for (int t = wid; t < ntile; t += 4) {
    const int kv0 = t * 64;
    f32x4 sf[4] = {};
#pragma unroll
    for (int f = 0; f < 4; ++f) {
      const u16* kp = kb + ((size_t)(t * 16 + f * 4) << 9) + lane8;
#pragma unroll
      for (int c = 0; c < 4; ++c)
        sf[f] = mfma16(qf[c], *(const bf16x8*)(kp + (c << 9)), sf[f]);
    }
    float tm[4], al[4], ts[4];
#pragma unroll
    for (int r = 0; r < 4; ++r) {
      float mx = -INFINITY;
#pragma unroll
      for (int f = 0; f < 4; ++f) {
        const int j = kv0 + f * 16 + l4;
        const float v = (j < klen) ? sf[f][r] * SC : -INFINITY;
        sf[f][r] = v;
        mx = fmaxf(mx, v);
      }
      tm[r] = mx;
    }
#pragma unroll
    for (int mk = 8; mk >= 1; mk >>= 1)
#pragma unroll
      for (int r = 0; r < 4; ++r) tm[r] = fmaxf(tm[r], __shfl_xor(tm[r], mk));
#pragma unroll
    for (int r = 0; r < 4; ++r) {
      const float mn = fmaxf(m_r[r], tm[r]);
      al[r] = __expf(m_r[r] - mn);
      m_r[r] = mn;
      float sum = 0.f;
#pragma unroll
      for (int f = 0; f < 4; ++f) {
        const float p = __expf(sf[f][r] - mn);
        sf[f][r] = p;
        sum += p;
      }
      ts[r] = sum;
    }
#pragma unroll
    for (int mk = 8; mk >= 1; mk >>= 1)
#pragma unroll
      for (int r = 0; r < 4; ++r) ts[r] += __shfl_xor(ts[r], mk);
#pragma unroll
    for (int r = 0; r < 4; ++r) s_r[r] = s_r[r] * al[r] + ts[r];
    if (l4 == 0) {
#pragma unroll
      for (int r = 0; r < 4; ++r) alpha_w[wid][g * 4 + r] = al[r];
    }
#pragma unroll
    for (int r = 0; r < 4; ++r)
#pragma unroll
      for (int f = 0; f < 4; ++f)
        p_lds[wid][g * 4 + r][f * 16 + l4] = f2bf(sf[f][r]);
    const float af = alpha_w[wid][l4];     // rescale factor for col t = l4
#pragma unroll
    for (int d = 0; d < 8; ++d)
#pragma unroll
      for (int r = 0; r < 4; ++r) acc[d][r] *= af;
    const bf16x8 pf0 = *(const bf16x8*)&p_lds[wid][l4][g * 8];
    const bf16x8 pf1 = *(const bf16x8*)&p_lds[wid][l4][32 + g * 8];
#pragma unroll
    for (int d = 0; d < 8; ++d) {
      const u16* vr = vb + ((size_t)(t * 8 + d) << 10) + lane8;
      acc[d] = mfma16(*(const bf16x8*)vr, pf0, acc[d]);
      acc[d] = mfma16(*(const bf16x8*)(vr + 512), pf1, acc[d]);
    }
  }

  // ------- cross-wave combine (online-softmax merge) -------
  if (l4 == 0) {
#pragma unroll
    for (int r = 0; r < 4; ++r) { mw[wid][g * 4 + r] = m_r[r]; lw[wid][g * 4 + r] = s_r[r]; }
  }
  __syncthreads();   // all waves done with loop; p_lds/alpha now dead
  const float M4 = fmaxf(fmaxf(mw[0][l4], mw[1][l4]), fmaxf(mw[2][l4], mw[3][l4]));
  const float mysc = __expf(mw[wid][l4] - M4);   // my wave's factor for col l4
#pragma unroll
  for (int d = 0; d < 8; ++d)
#pragma unroll
    for (int r = 0; r < 4; ++r)
      accbuf[wid][l4][d * 16 + g * 4 + r] = acc[d][r] * mysc;
  __syncthreads();
  const int row = tid >> 4, col0 = (tid & 15) * 8;
  const float Mr = fmaxf(fmaxf(mw[0][row], mw[1][row]), fmaxf(mw[2][row], mw[3][row]));
  float den = 0.f;
#pragma unroll
  for (int w = 0; w < 4; ++w) den += lw[w][row] * __expf(mw[w][row] - Mr);
  const float inv = 1.0f / den;
  const int tt = q0 + row;
  if (tt < T_TOK) {
    float o[8];
#pragma unroll
    for (int c = 0; c < 8; ++c)
      o[c] = (accbuf[0][row][col0 + c] + accbuf[1][row][col0 + c] +
              accbuf[2][row][col0 + c] + accbuf[3][row][col0 + c]) * inv;
    uint4 ov;
    ov.x = pack2(o[0], o[1]); ov.y = pack2(o[2], o[3]);
    ov.z = pack2(o[4], o[5]); ov.w = pack2(o[6], o[7]);
    *(uint4*)(yb + ((size_t)(b * T_TOK + tt)) * NE + h * HD + col0) = ov;
  }
}

// ---------------- launcher ---------------------------------------------------
// ws layout (bytes), total ~170.1 MB (assumes ws_size >= that):
//   0        rope_cos (256KB) | 262144 rope_sin | 524288 x_bf16 (8.48MB)
//   9003008  W_bf16 [Wq|Wk|Wv|Wproj] (33.55MB) | 42557440 qpre f32 (16.96MB)
//   59514880 kpre f32 | 76472320 vtmp bf16 (8.48MB) | 84951040 q_bf16
//   93429760 K_eff bf16 (tiled, 34.08MB) | 127508480 V tiled bf16 (34.08MB)
//   161587200 y_bf16 (8.48MB) -> end 170065920
extern "C" void kernel_launch(void* const* d_in, const int* in_sizes, int n_in,
                              void* d_out, int out_size, void* d_ws, size_t ws_size,
                              hipStream_t stream) {
  (void)in_sizes; (void)n_in; (void)out_size; (void)ws_size;
  const float* x   = (const float*)d_in[0];
  const float* Wq  = (const float*)d_in[1];
  const float* Wk  = (const float*)d_in[2];
  const float* Wv  = (const float*)d_in[3];
  const float* Wp  = (const float*)d_in[4];
  const float* qnw = (const float*)d_in[5];
  const float* qnb = (const float*)d_in[6];
  const float* knw = (const float*)d_in[7];
  const float* knb = (const float*)d_in[8];
  const float* ck  = (const float*)d_in[9];
  const float* cv  = (const float*)d_in[10];
  const int* pcs = (const int*)d_in[11];
  const int* pge = (const int*)d_in[12];
  const int* ple = (const int*)d_in[13];
  float* out = (float*)d_out;
  char* w = (char*)d_ws;

  float* rc   = (float*)(w + 0);
  float* rs   = (float*)(w + 262144);
  u16* xb     = (u16*)(w + 524288);
  u16* wb     = (u16*)(w + 9003008);
  float* qpre = (float*)(w + 42557440);
  float* kpre = (float*)(w + 59514880);
  u16* vtmp   = (u16*)(w + 76472320);
  u16* qbuf   = (u16*)(w + 84951040);
  u16* keff   = (u16*)(w + 93429760);
  u16* vtb    = (u16*)(w + 127508480);
  u16* yb     = (u16*)(w + 161587200);

  conv_bf16<<<10262, 256, 0, stream>>>(x, Wq, Wk, Wv, Wp, xb, wb);
  rope_tab_k<<<256, 256, 0, stream>>>(rc, rs);
  gemm_k<0><<<dim3(17, 48), 256, 0, stream>>>(xb, wb, qpre, kpre, vtmp);
  ln_rope_k<<<dim3(BT, 2), 256, 0, stream>>>(qpre, kpre, qnw, qnb, knw, knb,
                                             rc, rs, qbuf, keff, pcs, pge, ple);
  gather_k_k<<<dim3(260, NH, 2), 256, 0, stream>>>(ck, keff, pcs, pge, ple);
  vt_fill_k<<<dim3(65, NH, 2), 256, 0, stream>>>(cv, vtmp, vtb, pcs, pge, ple);
  attn_k<<<2080, 256, 0, stream>>>(qbuf, keff, vtb, yb, pcs, pge, ple);
  gemm_k<1><<<dim3(17, 16), 256, 0, stream>>>(yb, wb + (size_t)3 * WN, out,
                                              nullptr, nullptr);
}

// Round 10
// 636.439 us; speedup vs baseline: 1.7325x; 1.0012x over previous
//
#include <hip/hip_runtime.h>
#include <hip/hip_bf16.h>
#include <cstdint>
#include <cstddef>
#include <math.h>

// ---------------- problem constants ----------------
#define T_TOK 1035      // TOTAL_TOKENS
#define BT    2070      // B*T
#define NE    2048      // n_embd
#define NH    16
#define HD    128
#define CACHE_SZ 5175
#define SINK  1035
#define MAXA  4140      // LOCAL_ATTN_SIZE*TOTAL_TOKENS
#define KPAD  4160      // MAXA rounded up to 64
#define PRE   11        // POSE+YAW
#define WN    4194304   // 2048*2048
#define XN    4239360   // 2070*2048

typedef unsigned short u16;
typedef __attribute__((ext_vector_type(8))) short bf16x8;
typedef __attribute__((ext_vector_type(4))) float f32x4;

__device__ __forceinline__ u16 f2bf(float f) {
  union { float f; uint32_t u; } v; v.f = f;
  return (u16)((v.u + 0x7FFFu + ((v.u >> 16) & 1)) >> 16);
}
__device__ __forceinline__ uint32_t pack2(float a, float b) {
  return (uint32_t)f2bf(a) | ((uint32_t)f2bf(b) << 16);
}

typedef __attribute__((address_space(1))) const void gvoid;
typedef __attribute__((address_space(3))) void lvoid;
__device__ __forceinline__ void gload16(const void* g, void* l) {
  __builtin_amdgcn_global_load_lds((gvoid*)g, (lvoid*)l, 16, 0, 0);
}
__device__ __forceinline__ f32x4 mfma16(bf16x8 a, bf16x8 b, f32x4 c) {
  return __builtin_amdgcn_mfma_f32_16x16x32_bf16(a, b, c, 0, 0, 0);
}

// MFMA-native tiled layouts (u16 index within one (b,h) plane of size KPAD*HD):
// K: element (key j, dim e) -> [j>>6][(j>>4)&3][e>>5][(e>>3)&3][j&15][e&7]
__device__ __forceinline__ size_t kt_idx(int j, int e) {
  return ((size_t)(((((j >> 6) * 4 + ((j >> 4) & 3)) * 4 + (e >> 5)) * 4 +
                    ((e >> 3) & 3)))) * 128 + (j & 15) * 8 + (e & 7);
}
// V: element (key j, dim v)  -> [j>>6][v>>4][(j>>3)&7][v&15][j&7]

// ---------------- cache-window arithmetic (device, from runtime scalars) ----
struct CacheMap {
  int cache_start, klen, pos_new;   // pos_new: eff-index where new tokens begin
  int num_evicted, num_rolled;
  bool evict;
};
__device__ __forceinline__ CacheMap cache_map(int cs, int ge, int le) {
  CacheMap m;
  const int ce = cs + T_TOK;
  m.evict = (ce > ge) && (T_TOK + le > CACHE_SZ);
  int nle;
  if (m.evict) {
    m.num_evicted = T_TOK + le - CACHE_SZ;
    m.num_rolled  = le - m.num_evicted - SINK;
    nle = le + (ce - ge) - m.num_evicted;
    m.pos_new = SINK + m.num_rolled;
  } else {
    m.num_evicted = 0; m.num_rolled = 0;
    nle = le + (ce - ge);
    m.pos_new = nle - T_TOK;
  }
  int csrt = nle - MAXA; if (csrt < 0) csrt = 0;
  m.cache_start = csrt;
  m.klen = nle - csrt;
  return m;
}
// eff index -> cache token index (>=0) or new-token t encoded as -1-t
__device__ __forceinline__ int eff_src(const CacheMap& m, int e) {
  if (m.evict) {
    if (e < SINK) return e;
    if (e < m.pos_new) return e + m.num_evicted;
    return -1 - (e - m.pos_new);
  } else {
    if (e < m.pos_new) return e;
    return -1 - (e - m.pos_new);
  }
}

// ---------------- kernel 1: f32 -> bf16 convert (x + 4 weights) -------------
__global__ __launch_bounds__(256) void conv_bf16(
    const float* __restrict__ x, const float* __restrict__ wq,
    const float* __restrict__ wk, const float* __restrict__ wv,
    const float* __restrict__ wp, u16* __restrict__ xb, u16* __restrict__ wb) {
  const size_t i8 = ((size_t)blockIdx.x * 256 + threadIdx.x) * 8;
  if (i8 >= (size_t)XN + 4ull * WN) return;
  const float* src; u16* dst;
  if (i8 < XN) { src = x + i8; dst = xb + i8; }
  else {
    const size_t w = i8 - XN;
    const int m = (int)(w >> 22);
    const size_t o = w & (WN - 1);
    src = (m == 0 ? wq : m == 1 ? wk : m == 2 ? wv : wp) + o;
    dst = wb + w;
  }
  float4 a = *(const float4*)src;
  float4 c = *(const float4*)(src + 4);
  uint4 o;
  o.x = pack2(a.x, a.y); o.y = pack2(a.z, a.w);
  o.z = pack2(c.x, c.y); o.w = pack2(c.z, c.w);
  *(uint4*)dst = o;
}

// ---------------- kernel 2: axial RoPE tables [1024][64] --------------------
__global__ __launch_bounds__(256) void rope_tab_k(float* __restrict__ rc,
                                                  float* __restrict__ rs) {
  const int idx = blockIdx.x * 256 + threadIdx.x;   // 65536 entries
  const int t = idx >> 6, p = idx & 63;
  const int fi = p & 31;
  const float pos = (p < 32) ? (float)(t & 31) : (float)(t >> 5);
  const float freq = exp2f(-(float)fi * 0.31143075889569023f); // log2(1000)/32
  const float ang = pos * freq;
  rc[idx] = cosf(ang);
  rs[idx] = sinf(ang);
}

// ---------------- kernel 3/8: bf16 GEMM, C = A @ Bw^T (NT) ------------------
template<int MODE>
__global__ __launch_bounds__(256) void gemm_k(const u16* __restrict__ A,
                                              const u16* __restrict__ Bw,
                                              float* __restrict__ o0,
                                              float* __restrict__ o1,
                                              u16* __restrict__ o2) {
  __shared__ u16 lA[128 * 64];
  __shared__ u16 lB[128 * 64];
  const int tid = threadIdx.x;
  const int m0 = blockIdx.x * 128;
  const int n0 = blockIdx.y * 128;
  const int lane = tid & 63, wid = tid >> 6;
  const int l4 = lane & 15, g = lane >> 4;
  const int wm = wid >> 1, wn = wid & 1;

  f32x4 acc[4][4] = {};

  const int srow = tid >> 3;          // 0..31
  const int cb = (tid & 7) * 16;      // byte col in 128B row

  for (int k0 = 0; k0 < NE; k0 += 64) {
#pragma unroll
    for (int i = 0; i < 4; ++i) {
      const int r = i * 32 + srow;
      const int scb = cb ^ ((r & 7) << 4);   // pre-swizzled global source col
      int am = m0 + r; if (am > BT - 1) am = BT - 1;
      gload16(A + (size_t)am * NE + k0 + (scb >> 1), &lA[r * 64 + (cb >> 1)]);
      gload16(Bw + (size_t)(n0 + r) * NE + k0 + (scb >> 1), &lB[r * 64 + (cb >> 1)]);
    }
    __syncthreads();
#pragma unroll
    for (int kk = 0; kk < 64; kk += 32) {
      bf16x8 af[4], bfr[4];
#pragma unroll
      for (int i = 0; i < 4; ++i) {
        const int ra = wm * 64 + i * 16 + l4;
        af[i] = *(const bf16x8*)&lA[(ra * 64 + kk + g * 8) ^ ((l4 & 7) << 3)];
        const int rb = wn * 64 + i * 16 + l4;
        bfr[i] = *(const bf16x8*)&lB[(rb * 64 + kk + g * 8) ^ ((l4 & 7) << 3)];
      }
#pragma unroll
      for (int i = 0; i < 4; ++i)
#pragma unroll
        for (int j = 0; j < 4; ++j)
          acc[i][j] = mfma16(af[i], bfr[j], acc[i][j]);
    }
    __syncthreads();
  }
#pragma unroll
  for (int i = 0; i < 4; ++i) {
#pragma unroll
    for (int j = 0; j < 4; ++j) {
      const int ng = n0 + wn * 64 + j * 16 + l4;
#pragma unroll
      for (int r = 0; r < 4; ++r) {
        const int m = m0 + wm * 64 + i * 16 + g * 4 + r;
        if (m < BT) {
          const float v = acc[i][j][r];
          if (MODE == 1) {
            o0[(size_t)m * NE + ng] = v;
          } else {
            if (n0 < NE)          o0[(size_t)m * NE + ng] = v;
            else if (n0 < 2 * NE) o1[(size_t)m * NE + (ng - NE)] = v;
            else                  o2[(size_t)m * NE + (ng - 2 * NE)] = f2bf(v);
          }
        }
      }
    }
  }
}

// ---------------- kernel 4: LayerNorm + axial RoPE, layout q / new-k --------
__device__ __forceinline__ void load8(const float* p, float* d) {
  float4 a = *(const float4*)p, b = *(const float4*)(p + 4);
  d[0]=a.x; d[1]=a.y; d[2]=a.z; d[3]=a.w; d[4]=b.x; d[5]=b.y; d[6]=b.z; d[7]=b.w;
}
__global__ __launch_bounds__(256) void ln_rope_k(
    const float* __restrict__ qpre, const float* __restrict__ kpre,
    const float* __restrict__ qw, const float* __restrict__ qbs,
    const float* __restrict__ kw, const float* __restrict__ kbs,
    const float* __restrict__ rc, const float* __restrict__ rs,
    u16* __restrict__ qb, u16* __restrict__ keff,
    const int* pcs, const int* pge, const int* ple) {
  const int row = blockIdx.x;       // 0..2069
  const int isk = blockIdx.y;       // 0:q 1:k
  const int tid = threadIdx.x;
  const float* src = (isk ? kpre : qpre) + (size_t)row * NE;
  float e[8];
  load8(src + tid * 8, e);
  float s = 0.f, ss = 0.f;
#pragma unroll
  for (int i = 0; i < 8; ++i) { s += e[i]; ss += e[i] * e[i]; }
#pragma unroll
  for (int mk = 32; mk >= 1; mk >>= 1) { s += __shfl_xor(s, mk); ss += __shfl_xor(ss, mk); }
  __shared__ float ps[4], pss[4];
  if ((tid & 63) == 0) { ps[tid >> 6] = s; pss[tid >> 6] = ss; }
  __syncthreads();
  s = ps[0] + ps[1] + ps[2] + ps[3];
  ss = pss[0] + pss[1] + pss[2] + pss[3];
  const float mu = s * (1.0f / NE);
  const float rstd = 1.0f / sqrtf(ss * (1.0f / NE) - mu * mu + 1e-5f);
  const int c0 = tid * 8;
  float wr[8], br[8];
  load8((isk ? kw : qw) + c0, wr);
  load8((isk ? kbs : qbs) + c0, br);
#pragma unroll
  for (int i = 0; i < 8; ++i) e[i] = (e[i] - mu) * rstd * wr[i] + br[i];
  const int b_ = row / T_TOK, t = row - b_ * T_TOK;
  if (t >= PRE) {
    const int timg = t - PRE;
    const int p0 = (c0 & 127) >> 1;     // pair index 0..60, multiple of 4
    float c4[4], s4[4];
    {
      float4 ca = *(const float4*)(rc + timg * 64 + p0);
      float4 sa = *(const float4*)(rs + timg * 64 + p0);
      c4[0]=ca.x; c4[1]=ca.y; c4[2]=ca.z; c4[3]=ca.w;
      s4[0]=sa.x; s4[1]=sa.y; s4[2]=sa.z; s4[3]=sa.w;
    }
#pragma unroll
    for (int p = 0; p < 4; ++p) {
      const float x0 = e[2*p], x1 = e[2*p+1];
      e[2*p]   = x0 * c4[p] - x1 * s4[p];
      e[2*p+1] = x0 * s4[p] + x1 * c4[p];
    }
  }
  uint4 o;
  o.x = pack2(e[0], e[1]); o.y = pack2(e[2], e[3]);
  o.z = pack2(e[4], e[5]); o.w = pack2(e[6], e[7]);
  const int h = c0 >> 7, d0 = c0 & 127;
  if (!isk) {
    *(uint4*)(qb + ((size_t)(b_ * NH + h) * T_TOK + t) * HD + d0) = o;
  } else {
    const CacheMap cm = cache_map(*pcs, *pge, *ple);
    const int jrow = cm.pos_new + t - cm.cache_start;
    if (jrow >= 0 && jrow < cm.klen)
      *(uint4*)(keff + (size_t)(b_ * NH + h) * (KPAD * HD) + kt_idx(jrow, d0)) = o;
  }
}

// ---------------- kernel 5: gather cache_k slice -> K_eff (tiled) -----------
// also zero-fills pad rows [klen, KPAD) so the last tile never reads poison.
__global__ __launch_bounds__(256) void gather_k_k(
    const float* __restrict__ cache_k, u16* __restrict__ keff,
    const int* pcs, const int* pge, const int* ple) {
  const CacheMap cm = cache_map(*pcs, *pge, *ple);
  const int b = blockIdx.z, h = blockIdx.y;
  const int j = blockIdx.x * 16 + (threadIdx.x >> 4);
  const int d0 = (threadIdx.x & 15) * 8;
  if (j >= KPAD) return;
  u16* dst = keff + (size_t)(b * NH + h) * (KPAD * HD) + kt_idx(j, d0);
  if (j >= cm.klen) {                 // pad rows: write zeros (finite)
    uint4 z = {0, 0, 0, 0};
    *(uint4*)dst = z;
    return;
  }
  const int s = eff_src(cm, cm.cache_start + j);
  if (s < 0) return;  // new tokens written by ln_rope_k
  const float* src = cache_k + (((size_t)b * CACHE_SZ + s) * NH + h) * HD + d0;
  float4 a = *(const float4*)src, c = *(const float4*)(src + 4);
  uint4 o;
  o.x = pack2(a.x, a.y); o.y = pack2(a.z, a.w);
  o.z = pack2(c.x, c.y); o.w = pack2(c.z, c.w);
  *(uint4*)dst = o;
}

// ---------------- kernel 6: build V (tiled MFMA-native) ---------------------
__global__ __launch_bounds__(256) void vt_fill_k(
    const float* __restrict__ cache_v, const u16* __restrict__ vtmp,
    u16* __restrict__ vt, const int* pcs, const int* pge, const int* ple) {
  const CacheMap cm = cache_map(*pcs, *pge, *ple);
  const int b = blockIdx.z, h = blockIdx.y;
  const int tile = blockIdx.x;
  const int j0 = tile * 64;
  const int tid = threadIdx.x;
  __shared__ u16 tbuf[128][72];    // [v][j_in_tile]
#pragma unroll
  for (int rd = 0; rd < 8; ++rd) {
    const int jt = rd * 8 + (tid >> 5);
    const int d0 = (tid & 31) * 4;
    const int j = j0 + jt;
    u16 r0 = 0, r1 = 0, r2 = 0, r3 = 0;    // pad cols MUST be finite (0)
    if (j < cm.klen) {
      const int s = eff_src(cm, cm.cache_start + j);
      if (s >= 0) {
        float4 a = *(const float4*)(cache_v + (((size_t)b * CACHE_SZ + s) * NH + h) * HD + d0);
        r0 = f2bf(a.x); r1 = f2bf(a.y); r2 = f2bf(a.z); r3 = f2bf(a.w);
      } else {
        const int t = -1 - s;
        const u16* p = vtmp + ((size_t)(b * T_TOK + t)) * NE + h * HD + d0;
        r0 = p[0]; r1 = p[1]; r2 = p[2]; r3 = p[3];
      }
    }
    tbuf[d0 + 0][jt] = r0; tbuf[d0 + 1][jt] = r1;
    tbuf[d0 + 2][jt] = r2; tbuf[d0 + 3][jt] = r3;
  }
  __syncthreads();
  // write tiled: [d(8)][cc(8)][l4(16)][8elem] — 1024 uint4 per tile
  u16* base = vt + (size_t)(b * NH + h) * (KPAD * HD) + (size_t)tile * 8192;
#pragma unroll
  for (int k = 0; k < 4; ++k) {
    const int o = k * 256 + tid;
    const int d = o >> 7, cc = (o >> 4) & 7, lv = o & 15;
    *(uint4*)(base + (size_t)o * 8) = *(const uint4*)&tbuf[d * 16 + lv][cc * 8];
  }
}

// ---------------- kernel 7: flash attention (KV-split across waves) ---------
// One block = 16 q-rows of one (b,h). 4 waves split the KV tiles (t%4==wid);
// end-of-block combine merges (m,l,acc) in TWO 64-dim passes so the combine
// LDS is 17.4KB instead of 33.8KB -> 6 blocks/CU (VGPR-capped) vs 4.
__global__ __launch_bounds__(256) void attn_k(
    const u16* __restrict__ qbuf, const u16* __restrict__ keff,
    const u16* __restrict__ vt, u16* __restrict__ yb,
    const int* pcs, const int* pge, const int* ple) {
  const CacheMap cm = cache_map(*pcs, *pge, *ple);
  const int klen = cm.klen;
  const int hw = blockIdx.x;                  // 0..2079
  const int id = (hw & 7) * 260 + (hw >> 3);  // bijective XCD swizzle (2080=8*260)
  const int qb_i = id % 65;
  const int bh = id / 65;
  const int h = bh & 15, b = bh >> 4;
  const int tid = threadIdx.x;
  const int lane = tid & 63, wid = tid >> 6;
  const int l4 = lane & 15, g = lane >> 4;
  const int q0 = qb_i * 16;
  const int qrow = q0 + l4;
  const int lane8 = lane * 8;

  // loop-phase LDS (p_lds + alpha) overlays the 2-pass combine buffer
  __shared__ __align__(16) char smraw[4 * 16 * 68 * 4];    // 17408 B
  u16 (*p_lds)[16][72] = (u16(*)[16][72])smraw;            // 9216 B
  float (*alpha_w)[16] = (float(*)[16])(smraw + 9216);     // 256 B
  float (*accbuf)[16][68] = (float(*)[16][68])smraw;       // reuse post-barrier
  __shared__ float mw[4][16], lw[4][16];

  bf16x8 qf[4] = {};
  if (qrow < T_TOK) {
    const u16* qp = qbuf + ((size_t)(b * NH + h) * T_TOK + qrow) * HD;
#pragma unroll
    for (int c = 0; c < 4; ++c) qf[c] = *(const bf16x8*)(qp + c * 32 + g * 8);
  }
  f32x4 acc[8] = {};
  float m_r[4] = {-INFINITY, -INFINITY, -INFINITY, -INFINITY};
  float s_r[4] = {0.f, 0.f, 0.f, 0.f};
  const u16* kb = keff + (size_t)(b * NH + h) * (KPAD * HD);
  const u16* vb = vt + (size_t)(b * NH + h) * (KPAD * HD);
  const float SC = 0.08838834764831845f;  // 1/sqrt(128)
  const int ntile = (klen + 63) >> 6;

  for (int t = wid; t < ntile; t += 4) {
    const int kv0 = t * 64;
    f32x4 sf[4] = {};
#pragma unroll
    for (int f = 0; f < 4; ++f) {
      const u16* kp = kb + ((size_t)(t * 16 + f * 4) << 9) + lane8;
#pragma unroll
      for (int c = 0; c < 4; ++c)
        sf[f] = mfma16(qf[c], *(const bf16x8*)(kp + (c << 9)), sf[f]);
    }
    float tm[4], al[4], ts[4];
#pragma unroll
    for (int r = 0; r < 4; ++r) {
      float mx = -INFINITY;
#pragma unroll
      for (int f = 0; f < 4; ++f) {
        const int j = kv0 + f * 16 + l4;
        const float v = (j < klen) ? sf[f][r] * SC : -INFINITY;
        sf[f][r] = v;
        mx = fmaxf(mx, v);
      }
      tm[r] = mx;
    }
#pragma unroll
    for (int mk = 8; mk >= 1; mk >>= 1)
#pragma unroll
      for (int r = 0; r < 4; ++r) tm[r] = fmaxf(tm[r], __shfl_xor(tm[r], mk));
#pragma unroll
    for (int r = 0; r < 4; ++r) {
      const float mn = fmaxf(m_r[r], tm[r]);
      al[r] = __expf(m_r[r] - mn);
      m_r[r] = mn;
      float sum = 0.f;
#pragma unroll
      for (int f = 0; f < 4; ++f) {
        const float p = __expf(sf[f][r] - mn);
        sf[f][r] = p;
        sum += p;
      }
      ts[r] = sum;
    }
#pragma unroll
    for (int mk = 8; mk >= 1; mk >>= 1)
#pragma unroll
      for (int r = 0; r < 4; ++r) ts[r] += __shfl_xor(ts[r], mk);
#pragma unroll
    for (int r = 0; r < 4; ++r) s_r[r] = s_r[r] * al[r] + ts[r];
    if (l4 == 0) {
#pragma unroll
      for (int r = 0; r < 4; ++r) alpha_w[wid][g * 4 + r] = al[r];
    }
#pragma unroll
    for (int r = 0; r < 4; ++r)
#pragma unroll
      for (int f = 0; f < 4; ++f)
        p_lds[wid][g * 4 + r][f * 16 + l4] = f2bf(sf[f][r]);
    const float af = alpha_w[wid][l4];     // rescale factor for col t = l4
#pragma unroll
    for (int d = 0; d < 8; ++d)
#pragma unroll
      for (int r = 0; r < 4; ++r) acc[d][r] *= af;
    const bf16x8 pf0 = *(const bf16x8*)&p_lds[wid][l4][g * 8];
    const bf16x8 pf1 = *(const bf16x8*)&p_lds[wid][l4][32 + g * 8];
#pragma unroll
    for (int d = 0; d < 8; ++d) {
      const u16* vr = vb + ((size_t)(t * 8 + d) << 10) + lane8;
      acc[d] = mfma16(*(const bf16x8*)vr, pf0, acc[d]);
      acc[d] = mfma16(*(const bf16x8*)(vr + 512), pf1, acc[d]);
    }
  }

  // ------- cross-wave combine (online-softmax merge, 2 passes of 64 dims) ---
  if (l4 == 0) {
#pragma unroll
    for (int r = 0; r < 4; ++r) { mw[wid][g * 4 + r] = m_r[r]; lw[wid][g * 4 + r] = s_r[r]; }
  }
  __syncthreads();   // loop done: p_lds/alpha dead; mw/lw visible
  const float M4 = fmaxf(fmaxf(mw[0][l4], mw[1][l4]), fmaxf(mw[2][l4], mw[3][l4]));
  const float mysc = __expf(mw[wid][l4] - M4);   // my wave's factor for col l4
  const int row = tid >> 4, c4 = (tid & 15) * 4;
  const float Mr = fmaxf(fmaxf(mw[0][row], mw[1][row]), fmaxf(mw[2][row], mw[3][row]));
  float den = 0.f;
#pragma unroll
  for (int w = 0; w < 4; ++w) den += lw[w][row] * __expf(mw[w][row] - Mr);
  const float inv = 1.0f / den;
  const int tt = q0 + row;
#pragma unroll
  for (int pass = 0; pass < 2; ++pass) {
#pragma unroll
    for (int dd = 0; dd < 4; ++dd) {
      const int d = pass * 4 + dd;
#pragma unroll
      for (int r = 0; r < 4; ++r)
        accbuf[wid][l4][dd * 16 + g * 4 + r] = acc[d][r] * mysc;
    }
    __syncthreads();
    if (tt < T_TOK) {
      float o[4];
#pragma unroll
      for (int c = 0; c < 4; ++c)
        o[c] = (accbuf[0][row][c4 + c] + accbuf[1][row][c4 + c] +
                accbuf[2][row][c4 + c] + accbuf[3][row][c4 + c]) * inv;
      uint2 ov;
      ov.x = pack2(o[0], o[1]); ov.y = pack2(o[2], o[3]);
      *(uint2*)(yb + ((size_t)(b * T_TOK + tt)) * NE + h * HD + pass * 64 + c4) = ov;
    }
    if (pass == 0) __syncthreads();   // protect accbuf before pass-1 overwrite
  }
}

// ---------------- launcher ---------------------------------------------------
// ws layout (bytes), total ~170.1 MB (assumes ws_size >= that):
//   0        rope_cos (256KB) | 262144 rope_sin | 524288 x_bf16 (8.48MB)
//   9003008  W_bf16 [Wq|Wk|Wv|Wproj] (33.55MB) | 42557440 qpre f32 (16.96MB)
//   59514880 kpre f32 | 76472320 vtmp bf16 (8.48MB) | 84951040 q_bf16
//   93429760 K_eff bf16 (tiled, 34.08MB) | 127508480 V tiled bf16 (34.08MB)
//   161587200 y_bf16 (8.48MB) -> end 170065920
extern "C" void kernel_launch(void* const* d_in, const int* in_sizes, int n_in,
                              void* d_out, int out_size, void* d_ws, size_t ws_size,
                              hipStream_t stream) {
  (void)in_sizes; (void)n_in; (void)out_size; (void)ws_size;
  const float* x   = (const float*)d_in[0];
  const float* Wq  = (const float*)d_in[1];
  const float* Wk  = (const float*)d_in[2];
  const float* Wv  = (const float*)d_in[3];
  const float* Wp  = (const float*)d_in[4];
  const float* qnw = (const float*)d_in[5];
  const float* qnb = (const float*)d_in[6];
  const float* knw = (const float*)d_in[7];
  const float* knb = (const float*)d_in[8];
  const float* ck  = (const float*)d_in[9];
  const float* cv  = (const float*)d_in[10];
  const int* pcs = (const int*)d_in[11];
  const int* pge = (const int*)d_in[12];
  const int* ple = (const int*)d_in[13];
  float* out = (float*)d_out;
  char* w = (char*)d_ws;

  float* rc   = (float*)(w + 0);
  float* rs   = (float*)(w + 262144);
  u16* xb     = (u16*)(w + 524288);
  u16* wb     = (u16*)(w + 9003008);
  float* qpre = (float*)(w + 42557440);
  float* kpre = (float*)(w + 59514880);
  u16* vtmp   = (u16*)(w + 76472320);
  u16* qbuf   = (u16*)(w + 84951040);
  u16* keff   = (u16*)(w + 93429760);
  u16* vtb    = (u16*)(w + 127508480);
  u16* yb     = (u16*)(w + 161587200);

  conv_bf16<<<10262, 256, 0, stream>>>(x, Wq, Wk, Wv, Wp, xb, wb);
  rope_tab_k<<<256, 256, 0, stream>>>(rc, rs);
  gemm_k<0><<<dim3(17, 48), 256, 0, stream>>>(xb, wb, qpre, kpre, vtmp);
  ln_rope_k<<<dim3(BT, 2), 256, 0, stream>>>(qpre, kpre, qnw, qnb, knw, knb,
                                             rc, rs, qbuf, keff, pcs, pge, ple);
  gather_k_k<<<dim3(260, NH, 2), 256, 0, stream>>>(ck, keff, pcs, pge, ple);
  vt_fill_k<<<dim3(65, NH, 2), 256, 0, stream>>>(cv, vtmp, vtb, pcs, pge, ple);
  attn_k<<<2080, 256, 0, stream>>>(qbuf, keff, vtb, yb, pcs, pge, ple);
  gemm_k<1><<<dim3(17, 16), 256, 0, stream>>>(yb, wb + (size_t)3 * WN, out,
                                              nullptr, nullptr);
}